// Round 12
// baseline (2529.991 us; speedup 1.0000x reference)
//
#include <hip/hip_runtime.h>
#include <hip/hip_bf16.h>

// Model dims (fixed by reference)
#define LL 8
#define DD 1024
#define HH 16
#define DHH 64
#define SS 1024
#define BB 4
#define VV 32000
#define MM (BB * SS)   // 4096 rows

typedef unsigned short u16;
typedef __attribute__((ext_vector_type(8))) short short8v;   // 8 bf16 (4 VGPRs)
typedef __attribute__((ext_vector_type(4))) float f32x4;
typedef unsigned int __attribute__((address_space(1))) guint;
typedef unsigned int __attribute__((address_space(3))) luint;

__device__ __forceinline__ float bf2f_lo(unsigned u) { return __uint_as_float(u << 16); }
__device__ __forceinline__ u16 f2bf(float f) {
  unsigned x = __float_as_uint(f);
  return (u16)((x + 0x7fffu + ((x >> 16) & 1u)) >> 16);
}

// ---------------------------------------------------------------------------
// Embedding
// ---------------------------------------------------------------------------
__global__ __launch_bounds__(256) void embed_kernel(
    const int* __restrict__ idx, const float* __restrict__ tok,
    const float* __restrict__ pos, float* __restrict__ x) {
  int i = blockIdx.x * blockDim.x + threadIdx.x;
  int elem = i * 4;
  int row = elem / DD;
  int d = elem % DD;
  int s = row % SS;
  int t = idx[row];
  float4 tv = *(const float4*)(tok + (size_t)t * DD + d);
  float4 pv = *(const float4*)(pos + (size_t)s * DD + d);
  tv.x += pv.x; tv.y += pv.y; tv.z += pv.z; tv.w += pv.w;
  *(float4*)(x + (size_t)elem) = tv;
}

// ---------------------------------------------------------------------------
// LayerNorm over D=1024 (fp32 in, bf16 out)
// ---------------------------------------------------------------------------
__global__ __launch_bounds__(256) void ln_bf16_kernel(
    const float* __restrict__ x, const float* __restrict__ sc,
    const float* __restrict__ bi, u16* __restrict__ out) {
  const int row = blockIdx.x;
  const int tid = threadIdx.x;
  __shared__ float red[4];
  float4 v = ((const float4*)(x + (size_t)row * DD))[tid];
  float s = v.x + v.y + v.z + v.w;
  #pragma unroll
  for (int off = 32; off; off >>= 1) s += __shfl_down(s, off);
  if ((tid & 63) == 0) red[tid >> 6] = s;
  __syncthreads();
  float mean = (red[0] + red[1] + red[2] + red[3]) * (1.f / DD);
  float dx = v.x - mean, dy = v.y - mean, dz = v.z - mean, dw = v.w - mean;
  float vs = dx * dx + dy * dy + dz * dz + dw * dw;
  __syncthreads();
  #pragma unroll
  for (int off = 32; off; off >>= 1) vs += __shfl_down(vs, off);
  if ((tid & 63) == 0) red[tid >> 6] = vs;
  __syncthreads();
  float var = (red[0] + red[1] + red[2] + red[3]) * (1.f / DD);
  float rstd = rsqrtf(var + 1e-5f);
  float4 s4 = ((const float4*)sc)[tid];
  float4 b4 = ((const float4*)bi)[tid];
  ushort4 o;
  o.x = f2bf(dx * rstd * s4.x + b4.x);
  o.y = f2bf(dy * rstd * s4.y + b4.y);
  o.z = f2bf(dz * rstd * s4.z + b4.z);
  o.w = f2bf(dw * rstd * s4.w + b4.w);
  *(ushort4*)(out + (size_t)row * DD + tid * 4) = o;
}

// ---------------------------------------------------------------------------
// Weight transpose + fp32->bf16: W [l][K][N] (or head-blocked) -> BT rows [N][K]
// ---------------------------------------------------------------------------
template <bool HEADW>
__global__ __launch_bounds__(256) void convT_kernel(
    const float* __restrict__ W, u16* __restrict__ BT, int K, int N,
    size_t lstride) {
  __shared__ float tile[32][33];
  const int n0 = blockIdx.x * 32, k0 = blockIdx.y * 32, l = blockIdx.z;
  const int tx = threadIdx.x & 31, ty = threadIdx.x >> 5;
  const float* Wl;
  int ld;
  if (HEADW) {
    const int h = n0 >> 6;
    Wl = W + ((size_t)(l * HH + h) * K) * 64 + (n0 & 63);
    ld = 64;
  } else {
    Wl = W + (size_t)l * K * N + n0;
    ld = N;
  }
  #pragma unroll
  for (int i = 0; i < 4; ++i)
    tile[ty + 8 * i][tx] = Wl[(size_t)(k0 + ty + 8 * i) * ld + tx];
  __syncthreads();
  u16* out = BT + (size_t)l * lstride;
  #pragma unroll
  for (int i = 0; i < 4; ++i)
    out[(size_t)(n0 + ty + 8 * i) * K + k0 + tx] = f2bf(tile[tx][ty + 8 * i]);
}

// ===========================================================================
// Shared schedule macros
// ===========================================================================
#define BARRIER __builtin_amdgcn_s_barrier()
#define MEMFENCE asm volatile("" ::: "memory")
#define MROW(F, AQ, B0,B1,B2,B3) \
  acc[F][0] = __builtin_amdgcn_mfma_f32_16x16x32_bf16(AQ, B0, acc[F][0], 0, 0, 0); \
  acc[F][1] = __builtin_amdgcn_mfma_f32_16x16x32_bf16(AQ, B1, acc[F][1], 0, 0, 0); \
  acc[F][2] = __builtin_amdgcn_mfma_f32_16x16x32_bf16(AQ, B2, acc[F][2], 0, 0, 0); \
  acc[F][3] = __builtin_amdgcn_mfma_f32_16x16x32_bf16(AQ, B3, acc[F][3], 0, 0, 0);

// ===========================================================================
// gemm8: 256x256 tile, 8 waves, register-double-buffered 4-phase pipeline
// (R6-verified). Used for the big GEMMs: MLP1 / LM head.
// ===========================================================================
#define LDA_(BUF, KH, F) \
  (*(const short8v*)&As[BUF][KH][(wm * 128 + (F) * 16 + (lane & 15)) * 32 + rg])
#define LDB_(BUF, KH, NF) \
  (*(const short8v*)&Bs[BUF][KH][(wn * 64 + (NF) * 16 + (lane & 15)) * 32 + rg])
#define LDS_A(S0,S1,S2,S3, BUF, KH, FB) { \
  S0 = LDA_(BUF, KH, (FB) + 0); S1 = LDA_(BUF, KH, (FB) + 1); \
  S2 = LDA_(BUF, KH, (FB) + 2); S3 = LDA_(BUF, KH, (FB) + 3); }
#define LDS_B(S0,S1,S2,S3, BUF, KH) { \
  S0 = LDB_(BUF, KH, 0); S1 = LDB_(BUF, KH, 1); \
  S2 = LDB_(BUF, KH, 2); S3 = LDB_(BUF, KH, 3); }
#define STAGE_A(BUF, KH, KT) do { \
  __builtin_amdgcn_global_load_lds((const guint*)(Abase + (KT) * 64 + (KH) * 32), \
      (luint*)(&As[BUF][KH][tid * 8]), 16, 0, 0); \
  __builtin_amdgcn_global_load_lds((const guint*)(Abase + (size_t)128 * K + (KT) * 64 + (KH) * 32), \
      (luint*)(&As[BUF][KH][(tid + 512) * 8]), 16, 0, 0); \
} while (0)
#define STAGE_B(BUF, KH, KT) do { \
  __builtin_amdgcn_global_load_lds((const guint*)(Bbase + (KT) * 64 + (KH) * 32), \
      (luint*)(&Bs[BUF][KH][tid * 8]), 16, 0, 0); \
  __builtin_amdgcn_global_load_lds((const guint*)(Bbase + (size_t)128 * K + (KT) * 64 + (KH) * 32), \
      (luint*)(&Bs[BUF][KH][(tid + 512) * 8]), 16, 0, 0); \
} while (0)
#define MFMA16S(FB, A0,A1,A2,A3, B0,B1,B2,B3) \
  MROW((FB) + 0, A0, B0,B1,B2,B3) MROW((FB) + 1, A1, B0,B1,B2,B3) \
  MROW((FB) + 2, A2, B0,B1,B2,B3) MROW((FB) + 3, A3, B0,B1,B2,B3)

#define TILE4(CUR, KT, ST1, ST2, V1STR, V3STR, LD4, LGK4STR) { \
  const int cur_ = (CUR); \
  /* ph1 */ \
  MEMFENCE; \
  LDS_A(aN0,aN1,aN2,aN3, cur_, 0, 4); \
  if (ST1) { STAGE_A(cur_ ^ 1, 1, (KT) + 1); } \
  asm volatile("s_waitcnt " V1STR ::: "memory"); \
  asm volatile("s_waitcnt lgkmcnt(4)" ::: "memory"); \
  BARRIER; \
  __builtin_amdgcn_s_setprio(1); \
  MFMA16S(0, aP0,aP1,aP2,aP3, bP0,bP1,bP2,bP3); \
  __builtin_amdgcn_s_setprio(0); \
  /* ph2 */ \
  MEMFENCE; \
  LDS_A(aP0,aP1,aP2,aP3, cur_, 1, 0); \
  LDS_B(bN0,bN1,bN2,bN3, cur_, 1); \
  if (ST1) { STAGE_B(cur_ ^ 1, 1, (KT) + 1); } \
  asm volatile("s_waitcnt lgkmcnt(8)" ::: "memory"); \
  BARRIER; \
  __builtin_amdgcn_s_setprio(1); \
  MFMA16S(4, aN0,aN1,aN2,aN3, bP0,bP1,bP2,bP3); \
  __builtin_amdgcn_s_setprio(0); \
  /* ph3 */ \
  MEMFENCE; \
  LDS_A(aN0,aN1,aN2,aN3, cur_, 1, 4); \
  if (ST2) { STAGE_A(cur_, 0, (KT) + 2); } \
  asm volatile("s_waitcnt " V3STR ::: "memory"); \
  asm volatile("s_waitcnt lgkmcnt(4)" ::: "memory"); \
  BARRIER; \
  __builtin_amdgcn_s_setprio(1); \
  MFMA16S(0, aP0,aP1,aP2,aP3, bN0,bN1,bN2,bN3); \
  __builtin_amdgcn_s_setprio(0); \
  /* ph4 */ \
  MEMFENCE; \
  if (LD4) { LDS_A(aP0,aP1,aP2,aP3, cur_ ^ 1, 0, 0); \
             LDS_B(bP0,bP1,bP2,bP3, cur_ ^ 1, 0); } \
  if (ST2) { STAGE_B(cur_, 0, (KT) + 2); } \
  asm volatile("s_waitcnt " LGK4STR ::: "memory"); \
  BARRIER; \
  __builtin_amdgcn_s_setprio(1); \
  MFMA16S(4, aN0,aN1,aN2,aN3, bN0,bN1,bN2,bN3); \
  __builtin_amdgcn_s_setprio(0); \
}

template <bool BIAS, bool RELU, bool RESID, bool OBF16>
__global__ __launch_bounds__(512, 2) void gemm8(
    const u16* __restrict__ A, const u16* __restrict__ BT,
    const float* __restrict__ bias, const float* __restrict__ resid,
    void* __restrict__ Cv, int M, int N, int K) {
  __shared__ u16 As[2][2][8192];
  __shared__ u16 Bs[2][2][8192];
  const int tid = threadIdx.x;
  const int lane = tid & 63, wave = tid >> 6;
  const int wm = wave >> 2, wn = wave & 3;
  const int nwg = gridDim.x;
  const int bid = blockIdx.x;
  const int wg = ((nwg & 7) == 0) ? ((bid & 7) * (nwg >> 3) + (bid >> 3)) : bid;
  const int nmt = M >> 8;
  const int m0 = (wg % nmt) * 256;
  const int n0 = (wg / nmt) * 256;
  const int NT = K >> 6;
  const int sr = tid >> 2;
  const int ssc = (((tid & 3) ^ ((tid >> 3) & 3)) * 8);  // pre-swizzled chunk
  const u16* Abase = A + (size_t)(m0 + sr) * K + ssc;
  const u16* Bbase = BT + (size_t)(n0 + sr) * K + ssc;
  const int rg = (((lane >> 4) ^ ((lane >> 1) & 3)) * 8);  // read-chunk XOR

  f32x4 acc[8][4] = {};
  short8v aP0, aP1, aP2, aP3, aN0, aN1, aN2, aN3;
  short8v bP0, bP1, bP2, bP3, bN0, bN1, bN2, bN3;

  STAGE_A(0, 0, 0); STAGE_B(0, 0, 0);
  STAGE_A(0, 1, 0); STAGE_B(0, 1, 0);
  STAGE_A(1, 0, 1); STAGE_B(1, 0, 1);
  asm volatile("s_waitcnt vmcnt(8)" ::: "memory");
  BARRIER;
  MEMFENCE;
  LDS_A(aP0,aP1,aP2,aP3, 0, 0, 0);
  LDS_B(bP0,bP1,bP2,bP3, 0, 0);

  int kt = 0;
  for (; kt < NT - 2; ++kt) {
    TILE4(kt & 1, kt, true, true, "vmcnt(6)", "vmcnt(6)", true, "lgkmcnt(8)");
  }
  TILE4(kt & 1, kt, true, false, "vmcnt(6)", "vmcnt(4)", true, "lgkmcnt(8)");
  ++kt;
  TILE4(kt & 1, kt, false, false, "vmcnt(0)", "vmcnt(0)", false, "lgkmcnt(0)");

  #pragma unroll
  for (int f = 0; f < 8; ++f) {
    #pragma unroll
    for (int n = 0; n < 4; ++n) {
      const int col = n0 + wn * 64 + n * 16 + (lane & 15);
      #pragma unroll
      for (int r = 0; r < 4; ++r) {
        const int row = m0 + wm * 128 + f * 16 + (lane >> 4) * 4 + r;
        float v = acc[f][n][r];
        if (BIAS) v += bias[col];
        if (RELU) v = fmaxf(v, 0.f);
        if (RESID) v += resid[(size_t)row * N + col];
        if (OBF16)
          ((u16*)Cv)[(size_t)row * N + col] = f2bf(v);
        else
          ((float*)Cv)[(size_t)row * N + col] = v;
      }
    }
  }
}

// ===========================================================================
// gemm4p: 128x128 tile, 4 waves (2x2), R6 pipeline halved; ~4 blocks/CU.
// Used for QK / V^T / proj / MLP2.
// ===========================================================================
#define LDA4_(BUF, KH, F) \
  (*(const short8v*)&As[BUF][KH][(wm * 64 + (F) * 16 + (lane & 15)) * 32 + rg])
#define LDB4_(BUF, KH, NF) \
  (*(const short8v*)&Bs[BUF][KH][(wn * 64 + (NF) * 16 + (lane & 15)) * 32 + rg])
#define STAGE_A4(BUF, KH, KT) do { \
  __builtin_amdgcn_global_load_lds((const guint*)(Abase + (KT) * 64 + (KH) * 32), \
      (luint*)(&As[BUF][KH][tid * 8]), 16, 0, 0); \
  __builtin_amdgcn_global_load_lds((const guint*)(Abase + (size_t)64 * K + (KT) * 64 + (KH) * 32), \
      (luint*)(&As[BUF][KH][(tid + 256) * 8]), 16, 0, 0); \
} while (0)
#define STAGE_B4(BUF, KH, KT) do { \
  __builtin_amdgcn_global_load_lds((const guint*)(Bbase + (KT) * 64 + (KH) * 32), \
      (luint*)(&Bs[BUF][KH][tid * 8]), 16, 0, 0); \
  __builtin_amdgcn_global_load_lds((const guint*)(Bbase + (size_t)64 * K + (KT) * 64 + (KH) * 32), \
      (luint*)(&Bs[BUF][KH][(tid + 256) * 8]), 16, 0, 0); \
} while (0)
#define MFMA8S(F0, F1, A0, A1, B0,B1,B2,B3) \
  MROW(F0, A0, B0,B1,B2,B3) MROW(F1, A1, B0,B1,B2,B3)

#define TILE4P(CUR, KT, ST1, ST2, V1STR, V3STR, LD4, LGK4STR) { \
  const int cur_ = (CUR); \
  MEMFENCE; \
  aN0 = LDA4_(cur_, 0, 2); aN1 = LDA4_(cur_, 0, 3); \
  if (ST1) { STAGE_A4(cur_ ^ 1, 1, (KT) + 1); } \
  asm volatile("s_waitcnt " V1STR ::: "memory"); \
  asm volatile("s_waitcnt lgkmcnt(2)" ::: "memory"); \
  BARRIER; \
  __builtin_amdgcn_s_setprio(1); \
  MFMA8S(0, 1, aP0, aP1, bP0,bP1,bP2,bP3); \
  __builtin_amdgcn_s_setprio(0); \
  MEMFENCE; \
  aP0 = LDA4_(cur_, 1, 0); aP1 = LDA4_(cur_, 1, 1); \
  bN0 = LDB4_(cur_, 1, 0); bN1 = LDB4_(cur_, 1, 1); \
  bN2 = LDB4_(cur_, 1, 2); bN3 = LDB4_(cur_, 1, 3); \
  if (ST1) { STAGE_B4(cur_ ^ 1, 1, (KT) + 1); } \
  asm volatile("s_waitcnt lgkmcnt(6)" ::: "memory"); \
  BARRIER; \
  __builtin_amdgcn_s_setprio(1); \
  MFMA8S(2, 3, aN0, aN1, bP0,bP1,bP2,bP3); \
  __builtin_amdgcn_s_setprio(0); \
  MEMFENCE; \
  aN0 = LDA4_(cur_, 1, 2); aN1 = LDA4_(cur_, 1, 3); \
  if (ST2) { STAGE_A4(cur_, 0, (KT) + 2); } \
  asm volatile("s_waitcnt " V3STR ::: "memory"); \
  asm volatile("s_waitcnt lgkmcnt(2)" ::: "memory"); \
  BARRIER; \
  __builtin_amdgcn_s_setprio(1); \
  MFMA8S(0, 1, aP0, aP1, bN0,bN1,bN2,bN3); \
  __builtin_amdgcn_s_setprio(0); \
  MEMFENCE; \
  if (LD4) { aP0 = LDA4_(cur_ ^ 1, 0, 0); aP1 = LDA4_(cur_ ^ 1, 0, 1); \
             bP0 = LDB4_(cur_ ^ 1, 0, 0); bP1 = LDB4_(cur_ ^ 1, 0, 1); \
             bP2 = LDB4_(cur_ ^ 1, 0, 2); bP3 = LDB4_(cur_ ^ 1, 0, 3); } \
  if (ST2) { STAGE_B4(cur_, 0, (KT) + 2); } \
  asm volatile("s_waitcnt " LGK4STR ::: "memory"); \
  BARRIER; \
  __builtin_amdgcn_s_setprio(1); \
  MFMA8S(2, 3, aN0, aN1, bN0,bN1,bN2,bN3); \
  __builtin_amdgcn_s_setprio(0); \
}

template <bool BIAS, bool RELU, bool RESID, bool OBF16>
__global__ __launch_bounds__(256, 2) void gemm4p(
    const u16* __restrict__ A, const u16* __restrict__ BT,
    const float* __restrict__ bias, const float* __restrict__ resid,
    void* __restrict__ Cv, int M, int N, int K) {
  __shared__ u16 As[2][2][4096];
  __shared__ u16 Bs[2][2][4096];
  const int tid = threadIdx.x;
  const int lane = tid & 63, wave = tid >> 6;
  const int wm = wave >> 1, wn = wave & 1;
  const int m0 = blockIdx.x * 128, n0 = blockIdx.y * 128;
  const int NT = K >> 6;
  const int sr = tid >> 2;
  const int ssc = (((tid & 3) ^ ((tid >> 3) & 3)) * 8);  // pre-swizzled chunk
  const u16* Abase = A + (size_t)(m0 + sr) * K + ssc;
  const u16* Bbase = BT + (size_t)(n0 + sr) * K + ssc;
  const int rg = (((lane >> 4) ^ ((lane >> 1) & 3)) * 8);

  f32x4 acc[4][4] = {};
  short8v aP0, aP1, aN0, aN1;
  short8v bP0, bP1, bP2, bP3, bN0, bN1, bN2, bN3;

  STAGE_A4(0, 0, 0); STAGE_B4(0, 0, 0);
  STAGE_A4(0, 1, 0); STAGE_B4(0, 1, 0);
  STAGE_A4(1, 0, 1); STAGE_B4(1, 0, 1);
  asm volatile("s_waitcnt vmcnt(8)" ::: "memory");
  BARRIER;
  MEMFENCE;
  aP0 = LDA4_(0, 0, 0); aP1 = LDA4_(0, 0, 1);
  bP0 = LDB4_(0, 0, 0); bP1 = LDB4_(0, 0, 1);
  bP2 = LDB4_(0, 0, 2); bP3 = LDB4_(0, 0, 3);

  int kt = 0;
  for (; kt < NT - 2; ++kt) {
    TILE4P(kt & 1, kt, true, true, "vmcnt(6)", "vmcnt(6)", true, "lgkmcnt(6)");
  }
  TILE4P(kt & 1, kt, true, false, "vmcnt(6)", "vmcnt(4)", true, "lgkmcnt(6)");
  ++kt;
  TILE4P(kt & 1, kt, false, false, "vmcnt(0)", "vmcnt(0)", false, "lgkmcnt(0)");

  #pragma unroll
  for (int f = 0; f < 4; ++f) {
    #pragma unroll
    for (int n = 0; n < 4; ++n) {
      const int col = n0 + wn * 64 + n * 16 + (lane & 15);
      #pragma unroll
      for (int r = 0; r < 4; ++r) {
        const int row = m0 + wm * 64 + f * 16 + (lane >> 4) * 4 + r;
        float v = acc[f][n][r];
        if (BIAS) v += bias[col];
        if (RELU) v = fmaxf(v, 0.f);
        if (RESID) v += resid[(size_t)row * N + col];
        if (OBF16)
          ((u16*)Cv)[(size_t)row * N + col] = f2bf(v);
        else
          ((float*)Cv)[(size_t)row * N + col] = v;
      }
    }
  }
}

// ---------------------------------------------------------------------------
// Fallback fp32 GEMM for LM head (A bf16, B fp32 [K][N], +bias)
// ---------------------------------------------------------------------------
__global__ __launch_bounds__(256) void gemm_fb(
    const u16* __restrict__ A, const float* __restrict__ B,
    const float* __restrict__ bias, float* __restrict__ C, int M, int N, int K) {
  __shared__ alignas(16) float Asm[16][68];
  __shared__ alignas(16) float Bsm[16][68];
  const int tid = threadIdx.x;
  const int tx = tid & 15, ty = tid >> 4;
  const int m0 = blockIdx.y * 64, n0 = blockIdx.x * 64;
  const int ar = tid >> 2, ac = (tid & 3) * 4;
  const int br = tid >> 4, bc = (tid & 15) * 4;
  float acc[4][4] = {};
  for (int k0 = 0; k0 < K; k0 += 16) {
    ushort4 au = *(const ushort4*)(A + (size_t)(m0 + ar) * K + k0 + ac);
    float4 bv = *(const float4*)(B + (size_t)(k0 + br) * N + n0 + bc);
    Asm[ac + 0][ar] = bf2f_lo(au.x);
    Asm[ac + 1][ar] = bf2f_lo(au.y);
    Asm[ac + 2][ar] = bf2f_lo(au.z);
    Asm[ac + 3][ar] = bf2f_lo(au.w);
    *(float4*)&Bsm[br][bc] = bv;
    __syncthreads();
    #pragma unroll
    for (int kk = 0; kk < 16; ++kk) {
      float4 a = *(const float4*)&Asm[kk][ty * 4];
      float4 b = *(const float4*)&Bsm[kk][tx * 4];
      acc[0][0] += a.x * b.x; acc[0][1] += a.x * b.y; acc[0][2] += a.x * b.z; acc[0][3] += a.x * b.w;
      acc[1][0] += a.y * b.x; acc[1][1] += a.y * b.y; acc[1][2] += a.y * b.z; acc[1][3] += a.y * b.w;
      acc[2][0] += a.z * b.x; acc[2][1] += a.z * b.y; acc[2][2] += a.z * b.z; acc[2][3] += a.z * b.w;
      acc[3][0] += a.w * b.x; acc[3][1] += a.w * b.y; acc[3][2] += a.w * b.z; acc[3][3] += a.w * b.w;
    }
    __syncthreads();
  }
  #pragma unroll
  for (int i = 0; i < 4; ++i) {
    const int m = m0 + ty * 4 + i;
    #pragma unroll
    for (int j = 0; j < 4; ++j) {
      const int n = n0 + tx * 4 + j;
      C[(size_t)m * N + n] = acc[i][j] + bias[n];
    }
  }
}

// ---------------------------------------------------------------------------
// MFMA flash attention — 8 waves, 128 q-rows/block, KB=64.
// qk rows of 2048: [0..1023]=Q heads, [1024..2047]=K heads.
// vt: [h*64+e][b*S+s] bf16 (stride MM), produced by the V^T gemm4p.
// Heaviest q-tiles first; per-wave-uniform 'active' guard (barriers uniform).
// ---------------------------------------------------------------------------
__global__ __launch_bounds__(512) void attn_mfma(
    const u16* __restrict__ qk, const u16* __restrict__ vt,
    u16* __restrict__ o) {
  __shared__ alignas(16) u16 Ksh[64 * 64];
  __shared__ alignas(16) u16 Vsh[64 * 64];
  __shared__ unsigned Plds[8][16 * 41];
  __shared__ float bcast[8][16];
  const int tid = threadIdx.x;
  const int lane = tid & 63, wave = tid >> 6;
  const int g = lane >> 4, qi = lane & 15;
  const int qt = (SS / 128 - 1) - blockIdx.x;   // heaviest first
  const int h = blockIdx.y, b = blockIdx.z;
  const int q0w = qt * 128 + wave * 16;
  const int ktmax = 2 * qt + 1;

  short8v qf0, qf1;
  {
    const u16* qp = qk + ((size_t)b * SS + q0w + qi) * 2048 + h * DHH + g * 8;
    qf0 = *(const short8v*)qp;
    qf1 = *(const short8v*)(qp + 32);
  }

  f32x4 oacc[4] = {};
  float mrow = -1e30f, lrow = 0.f;

  for (int kt = 0; kt <= ktmax; ++kt) {
    __syncthreads();
    {  // stage K tile + V^T tile (512 threads: 1 K-load + 1 V-load each)
      const int row = tid >> 3, ch = tid & 7;
      const int sch = ch ^ (row & 7);
      __builtin_amdgcn_global_load_lds(
          (const guint*)(qk + ((size_t)b * SS + kt * 64 + row) * 2048 + 1024 + h * DHH + sch * 8),
          (luint*)(Ksh + tid * 8), 16, 0, 0);
      __builtin_amdgcn_global_load_lds(
          (const guint*)(vt + ((size_t)(h * DHH + row)) * MM + b * SS + kt * 64 + sch * 8),
          (luint*)(Vsh + tid * 8), 16, 0, 0);
    }
    __syncthreads();

    const bool active = (kt * 64 <= q0w + 15);
    if (active) {
      f32x4 st[4] = {};
      #pragma unroll
      for (int t = 0; t < 4; ++t) {
        const int row = t * 16 + qi;
        const int swz = (row & 7) << 4;
        short8v kf0 = *(const short8v*)(Ksh + row * 64 + (((g * 16) ^ swz) >> 1));
        short8v kf1 = *(const short8v*)(Ksh + row * 64 + (((64 + g * 16) ^ swz) >> 1));
        st[t] = __builtin_amdgcn_mfma_f32_16x16x32_bf16(kf0, qf0, st[t], 0, 0, 0);
        st[t] = __builtin_amdgcn_mfma_f32_16x16x32_bf16(kf1, qf1, st[t], 0, 0, 0);
      }

      const int diag = q0w + qi - kt * 64;
      if (diag < 63) {
        #pragma unroll
        for (int t = 0; t < 4; ++t)
          #pragma unroll
          for (int r = 0; r < 4; ++r)
            if (t * 16 + 4 * g + r > diag) st[t][r] = -1e30f;
      }

      float mt = st[0][0];
      #pragma unroll
      for (int t = 0; t < 4; ++t)
        #pragma unroll
        for (int r = 0; r < 4; ++r) mt = fmaxf(mt, st[t][r]);
      mt = fmaxf(mt, __shfl_xor(mt, 16));
      mt = fmaxf(mt, __shfl_xor(mt, 32));
      const float mnew = fmaxf(mrow, mt * 0.125f);
      const float corr = __expf(mrow - mnew);
      float pl = 0.f;
      #pragma unroll
      for (int t = 0; t < 4; ++t) {
        #pragma unroll
        for (int r2 = 0; r2 < 2; ++r2) {
          float plo = __expf(fmaf(st[t][2 * r2], 0.125f, -mnew));
          float phi = __expf(fmaf(st[t][2 * r2 + 1], 0.125f, -mnew));
          pl += plo + phi;
          Plds[wave][qi * 41 + 8 * t + 2 * g + r2] =
              (unsigned)f2bf(plo) | ((unsigned)f2bf(phi) << 16);
        }
      }
      pl += __shfl_xor(pl, 16);
      pl += __shfl_xor(pl, 32);
      lrow = lrow * corr + pl;
      mrow = mnew;

      if (g == 0) bcast[wave][qi] = corr;
      float c0 = bcast[wave][g * 4 + 0];
      float c1 = bcast[wave][g * 4 + 1];
      float c2 = bcast[wave][g * 4 + 2];
      float c3 = bcast[wave][g * 4 + 3];
      #pragma unroll
      for (int dvt = 0; dvt < 4; ++dvt) {
        oacc[dvt][0] *= c0; oacc[dvt][1] *= c1;
        oacc[dvt][2] *= c2; oacc[dvt][3] *= c3;
      }

      union U8 { unsigned u[4]; short8v s8; };
      U8 pa0, pa1;
      #pragma unroll
      for (int c = 0; c < 4; ++c) {
        pa0.u[c] = Plds[wave][qi * 41 + g * 4 + c];
        pa1.u[c] = Plds[wave][qi * 41 + 16 + g * 4 + c];
      }
      #pragma unroll
      for (int dvt = 0; dvt < 4; ++dvt) {
        const int row = dvt * 16 + qi;
        const int swz = (row & 7) << 4;
        short8v v0 = *(const short8v*)(Vsh + row * 64 + (((g * 16) ^ swz) >> 1));
        short8v v1 = *(const short8v*)(Vsh + row * 64 + (((64 + g * 16) ^ swz) >> 1));
        oacc[dvt] = __builtin_amdgcn_mfma_f32_16x16x32_bf16(pa0.s8, v0, oacc[dvt], 0, 0, 0);
        oacc[dvt] = __builtin_amdgcn_mfma_f32_16x16x32_bf16(pa1.s8, v1, oacc[dvt], 0, 0, 0);
      }
    }
  }

  if (g == 0) bcast[wave][qi] = 1.f / lrow;
  float i0 = bcast[wave][g * 4 + 0];
  float i1 = bcast[wave][g * 4 + 1];
  float i2 = bcast[wave][g * 4 + 2];
  float i3 = bcast[wave][g * 4 + 3];
  #pragma unroll
  for (int dvt = 0; dvt < 4; ++dvt) {
    const int col = h * DHH + dvt * 16 + qi;
    o[((size_t)b * SS + q0w + g * 4 + 0) * DD + col] = f2bf(oacc[dvt][0] * i0);
    o[((size_t)b * SS + q0w + g * 4 + 1) * DD + col] = f2bf(oacc[dvt][1] * i1);
    o[((size_t)b * SS + q0w + g * 4 + 2) * DD + col] = f2bf(oacc[dvt][2] * i2);
    o[((size_t)b * SS + q0w + g * 4 + 3) * DD + col] = f2bf(oacc[dvt][3] * i3);
  }
}

// ---------------------------------------------------------------------------
extern "C" void kernel_launch(void* const* d_in, const int* in_sizes, int n_in,
                              void* d_out, int out_size, void* d_ws, size_t ws_size,
                              hipStream_t stream) {
  const int* idx = (const int*)d_in[0];
  const float* tok_emb = (const float*)d_in[1];
  const float* pos_emb = (const float*)d_in[2];
  const float* ln1_s = (const float*)d_in[3];
  const float* ln1_b = (const float*)d_in[4];
  const float* wq = (const float*)d_in[5];
  const float* wk = (const float*)d_in[6];
  const float* wv = (const float*)d_in[7];
  const float* wproj = (const float*)d_in[8];
  const float* ln2_s = (const float*)d_in[9];
  const float* ln2_b = (const float*)d_in[10];
  const float* w1 = (const float*)d_in[11];
  const float* b1 = (const float*)d_in[12];
  const float* w2 = (const float*)d_in[13];
  const float* b2 = (const float*)d_in[14];
  const float* lnf_s = (const float*)d_in[15];
  const float* lnf_b = (const float*)d_in[16];
  const float* lm_w = (const float*)d_in[17];
  const float* lm_b = (const float*)d_in[18];

  const size_t MD = (size_t)MM * DD;

  // d_out scratch (all dead before the LM GEMM writes d_out)
  u16* sc0 = (u16*)d_out;
  u16* BTqk = sc0;                                   // LL x [2048][1024]
  u16* BTv = BTqk + (size_t)LL * 2048 * DD;          // LL x [1024][1024] (dv rows)
  u16* BTp = BTv + (size_t)LL * DD * DD;
  u16* BTw1 = BTp + (size_t)LL * DD * DD;
  u16* BTw2 = BTw1 + (size_t)LL * DD * 4 * DD;
  u16* qkb = BTw2 + (size_t)LL * DD * 4 * DD;        // [M][2048]
  u16* vtb = qkb + (size_t)MM * 2048;                // [1024][4096]
  u16* ob = vtb + MD;
  u16* tmp = ob + MD;                                // [M][4096]

  // d_ws: x fp32 (16MB) + h bf16 (8MB) + BT(lm_w) bf16 (65.5MB) if room
  float* x = (float*)d_ws;
  u16* h = (u16*)((char*)d_ws + MD * 4);
  u16* BTlm = (u16*)((char*)d_ws + MD * 4 + MD * 2);
  const bool big_ws = ws_size >= (MD * 4 + MD * 2 + (size_t)VV * DD * 2);

  const dim3 blk(256);

  convT_kernel<true><<<dim3(DD / 32, DD / 32, LL), blk, 0, stream>>>(
      wq, BTqk, DD, DD, (size_t)2048 * DD);
  convT_kernel<true><<<dim3(DD / 32, DD / 32, LL), blk, 0, stream>>>(
      wk, BTqk + (size_t)DD * DD, DD, DD, (size_t)2048 * DD);
  convT_kernel<true><<<dim3(DD / 32, DD / 32, LL), blk, 0, stream>>>(
      wv, BTv, DD, DD, (size_t)DD * DD);
  convT_kernel<false><<<dim3(DD / 32, DD / 32, LL), blk, 0, stream>>>(
      wproj, BTp, DD, DD, (size_t)DD * DD);
  convT_kernel<false><<<dim3(4 * DD / 32, DD / 32, LL), blk, 0, stream>>>(
      w1, BTw1, DD, 4 * DD, (size_t)DD * 4 * DD);
  convT_kernel<false><<<dim3(DD / 32, 4 * DD / 32, LL), blk, 0, stream>>>(
      w2, BTw2, 4 * DD, DD, (size_t)4 * DD * DD);
  if (big_ws)
    convT_kernel<false><<<dim3(VV / 32, DD / 32, 1), blk, 0, stream>>>(
        lm_w, BTlm, DD, VV, (size_t)VV * DD);

  embed_kernel<<<(MM * DD / 4 + 255) / 256, blk, 0, stream>>>(idx, tok_emb, pos_emb, x);

  for (int l = 0; l < LL; ++l) {
    ln_bf16_kernel<<<MM, blk, 0, stream>>>(x, ln1_s + l * DD, ln1_b + l * DD, h);
    // Q+K fused (gemm4p): C = h @ [Wq|Wk], N=2048, 512 blocks
    gemm4p<false, false, false, true><<<dim3(MM / 128, 2048 / 128), blk, 0, stream>>>(
        h, BTqk + (size_t)l * 2048 * DD, nullptr, nullptr, qkb, MM, 2048, DD);
    // V^T direct (gemm4p, transposed operands): C[dv][s] = Wv^T . h^T
    gemm4p<false, false, false, true><<<dim3(DD / 128, MM / 128), blk, 0, stream>>>(
        BTv + (size_t)l * DD * DD, h, nullptr, nullptr, vtb, DD, MM, DD);
    attn_mfma<<<dim3(SS / 128, HH, BB), dim3(512), 0, stream>>>(qkb, vtb, ob);
    // Projection + residual (gemm4p)
    gemm4p<false, false, true, false><<<dim3(MM / 128, DD / 128), blk, 0, stream>>>(
        ob, BTp + (size_t)l * DD * DD, nullptr, x, x, MM, DD, DD);
    ln_bf16_kernel<<<MM, blk, 0, stream>>>(x, ln2_s + l * DD, ln2_b + l * DD, h);
    // MLP1 (gemm8 256^2, 1024 blocks)
    gemm8<true, true, false, true><<<dim3((MM / 256) * (4 * DD / 256)), dim3(512), 0, stream>>>(
        h, BTw1 + (size_t)l * DD * 4 * DD, b1 + (size_t)l * 4 * DD, nullptr, tmp,
        MM, 4 * DD, DD);
    // MLP2 + residual (gemm4p)
    gemm4p<true, false, true, false><<<dim3(MM / 128, DD / 128), blk, 0, stream>>>(
        tmp, BTw2 + (size_t)l * 4 * DD * DD, b2 + (size_t)l * DD, x, x, MM, DD, 4 * DD);
  }

  ln_bf16_kernel<<<MM, blk, 0, stream>>>(x, lnf_s, lnf_b, h);
  if (big_ws) {
    // LM head (gemm8 256^2)
    gemm8<true, false, false, false><<<dim3((MM / 256) * (VV / 256)), dim3(512), 0, stream>>>(
        h, BTlm, lm_b, nullptr, (float*)d_out, MM, VV, DD);
  } else {
    gemm_fb<<<dim3(VV / 64, MM / 64), blk, 0, stream>>>(
        h, lm_w, lm_b, (float*)d_out, MM, VV, DD);
  }
}

// Round 13
// 2396.410 us; speedup vs baseline: 1.0557x; 1.0557x over previous
//
#include <hip/hip_runtime.h>
#include <hip/hip_bf16.h>

// Model dims (fixed by reference)
#define LL 8
#define DD 1024
#define HH 16
#define DHH 64
#define SS 1024
#define BB 4
#define VV 32000
#define MM (BB * SS)   // 4096 rows

typedef unsigned short u16;
typedef __attribute__((ext_vector_type(8))) short short8v;   // 8 bf16 (4 VGPRs)
typedef __attribute__((ext_vector_type(4))) float f32x4;
typedef unsigned int __attribute__((address_space(1))) guint;
typedef unsigned int __attribute__((address_space(3))) luint;

__device__ __forceinline__ float bf2f_lo(unsigned u) { return __uint_as_float(u << 16); }
__device__ __forceinline__ u16 f2bf(float f) {
  unsigned x = __float_as_uint(f);
  return (u16)((x + 0x7fffu + ((x >> 16) & 1u)) >> 16);
}

// ---------------------------------------------------------------------------
// Embedding
// ---------------------------------------------------------------------------
__global__ __launch_bounds__(256) void embed_kernel(
    const int* __restrict__ idx, const float* __restrict__ tok,
    const float* __restrict__ pos, float* __restrict__ x) {
  int i = blockIdx.x * blockDim.x + threadIdx.x;
  int elem = i * 4;
  int row = elem / DD;
  int d = elem % DD;
  int s = row % SS;
  int t = idx[row];
  float4 tv = *(const float4*)(tok + (size_t)t * DD + d);
  float4 pv = *(const float4*)(pos + (size_t)s * DD + d);
  tv.x += pv.x; tv.y += pv.y; tv.z += pv.z; tv.w += pv.w;
  *(float4*)(x + (size_t)elem) = tv;
}

// ---------------------------------------------------------------------------
// LayerNorm over D=1024 (fp32 in, bf16 out)
// ---------------------------------------------------------------------------
__global__ __launch_bounds__(256) void ln_bf16_kernel(
    const float* __restrict__ x, const float* __restrict__ sc,
    const float* __restrict__ bi, u16* __restrict__ out) {
  const int row = blockIdx.x;
  const int tid = threadIdx.x;
  __shared__ float red[4];
  float4 v = ((const float4*)(x + (size_t)row * DD))[tid];
  float s = v.x + v.y + v.z + v.w;
  #pragma unroll
  for (int off = 32; off; off >>= 1) s += __shfl_down(s, off);
  if ((tid & 63) == 0) red[tid >> 6] = s;
  __syncthreads();
  float mean = (red[0] + red[1] + red[2] + red[3]) * (1.f / DD);
  float dx = v.x - mean, dy = v.y - mean, dz = v.z - mean, dw = v.w - mean;
  float vs = dx * dx + dy * dy + dz * dz + dw * dw;
  __syncthreads();
  #pragma unroll
  for (int off = 32; off; off >>= 1) vs += __shfl_down(vs, off);
  if ((tid & 63) == 0) red[tid >> 6] = vs;
  __syncthreads();
  float var = (red[0] + red[1] + red[2] + red[3]) * (1.f / DD);
  float rstd = rsqrtf(var + 1e-5f);
  float4 s4 = ((const float4*)sc)[tid];
  float4 b4 = ((const float4*)bi)[tid];
  ushort4 o;
  o.x = f2bf(dx * rstd * s4.x + b4.x);
  o.y = f2bf(dy * rstd * s4.y + b4.y);
  o.z = f2bf(dz * rstd * s4.z + b4.z);
  o.w = f2bf(dw * rstd * s4.w + b4.w);
  *(ushort4*)(out + (size_t)row * DD + tid * 4) = o;
}

// ---------------------------------------------------------------------------
// Weight transpose + fp32->bf16: W [l][K][N] (or head-blocked) -> BT rows [N][K]
// 64k x 32n tiles; ushort2 stores (128 B per 32-lane row, coalesced).
// grid (N/32, K/64, L), block 256.
// ---------------------------------------------------------------------------
template <bool HEADW>
__global__ __launch_bounds__(256) void convT_kernel(
    const float* __restrict__ W, u16* __restrict__ BT, int K, int N,
    size_t lstride) {
  __shared__ float tile[64][33];
  const int n0 = blockIdx.x * 32, k0 = blockIdx.y * 64, l = blockIdx.z;
  const int tx = threadIdx.x & 31, ty = threadIdx.x >> 5;
  const float* Wl;
  int ld;
  if (HEADW) {
    const int h = n0 >> 6;
    Wl = W + ((size_t)(l * HH + h) * K) * 64 + (n0 & 63);
    ld = 64;
  } else {
    Wl = W + (size_t)l * K * N + n0;
    ld = N;
  }
  #pragma unroll
  for (int i = 0; i < 8; ++i)
    tile[ty + 8 * i][tx] = Wl[(size_t)(k0 + ty + 8 * i) * ld + tx];
  __syncthreads();
  u16* out = BT + (size_t)l * lstride;
  const int kk = tx * 2;
  #pragma unroll
  for (int j = 0; j < 4; ++j) {
    const int nn = ty + 8 * j;
    ushort2 v;
    v.x = f2bf(tile[kk + 0][nn]);
    v.y = f2bf(tile[kk + 1][nn]);
    *(ushort2*)(out + (size_t)(n0 + nn) * K + k0 + kk) = v;
  }
}

// ---------------------------------------------------------------------------
// V transpose: vt[dv][s] = qkv[s][2048+dv]  (bf16, 32x32 tiles)
// ---------------------------------------------------------------------------
__global__ __launch_bounds__(256) void transpose_v(
    const u16* __restrict__ qkv, u16* __restrict__ vt) {
  __shared__ u16 t[32][33];
  const int s0 = blockIdx.x * 32, d0 = blockIdx.y * 32;
  const int tx = threadIdx.x & 31, ty = threadIdx.x >> 5;
  #pragma unroll
  for (int i = 0; i < 4; ++i)
    t[ty + 8 * i][tx] = qkv[(size_t)(s0 + ty + 8 * i) * 3072 + 2048 + d0 + tx];
  __syncthreads();
  #pragma unroll
  for (int i = 0; i < 4; ++i)
    vt[(size_t)(d0 + ty + 8 * i) * MM + s0 + tx] = t[tx][ty + 8 * i];
}

// ===========================================================================
// Shared schedule macros
// ===========================================================================
#define BARRIER __builtin_amdgcn_s_barrier()
#define MEMFENCE asm volatile("" ::: "memory")
#define MROW(F, AQ, B0,B1,B2,B3) \
  acc[F][0] = __builtin_amdgcn_mfma_f32_16x16x32_bf16(AQ, B0, acc[F][0], 0, 0, 0); \
  acc[F][1] = __builtin_amdgcn_mfma_f32_16x16x32_bf16(AQ, B1, acc[F][1], 0, 0, 0); \
  acc[F][2] = __builtin_amdgcn_mfma_f32_16x16x32_bf16(AQ, B2, acc[F][2], 0, 0, 0); \
  acc[F][3] = __builtin_amdgcn_mfma_f32_16x16x32_bf16(AQ, B3, acc[F][3], 0, 0, 0);

// ===========================================================================
// gemm8: 256x256 tile, 8 waves, register-double-buffered 4-phase pipeline
// (R6-verified). Used for the big GEMMs: QKV / MLP1 / LM head.
// ===========================================================================
#define LDA_(BUF, KH, F) \
  (*(const short8v*)&As[BUF][KH][(wm * 128 + (F) * 16 + (lane & 15)) * 32 + rg])
#define LDB_(BUF, KH, NF) \
  (*(const short8v*)&Bs[BUF][KH][(wn * 64 + (NF) * 16 + (lane & 15)) * 32 + rg])
#define LDS_A(S0,S1,S2,S3, BUF, KH, FB) { \
  S0 = LDA_(BUF, KH, (FB) + 0); S1 = LDA_(BUF, KH, (FB) + 1); \
  S2 = LDA_(BUF, KH, (FB) + 2); S3 = LDA_(BUF, KH, (FB) + 3); }
#define LDS_B(S0,S1,S2,S3, BUF, KH) { \
  S0 = LDB_(BUF, KH, 0); S1 = LDB_(BUF, KH, 1); \
  S2 = LDB_(BUF, KH, 2); S3 = LDB_(BUF, KH, 3); }
#define STAGE_A(BUF, KH, KT) do { \
  __builtin_amdgcn_global_load_lds((const guint*)(Abase + (KT) * 64 + (KH) * 32), \
      (luint*)(&As[BUF][KH][tid * 8]), 16, 0, 0); \
  __builtin_amdgcn_global_load_lds((const guint*)(Abase + (size_t)128 * K + (KT) * 64 + (KH) * 32), \
      (luint*)(&As[BUF][KH][(tid + 512) * 8]), 16, 0, 0); \
} while (0)
#define STAGE_B(BUF, KH, KT) do { \
  __builtin_amdgcn_global_load_lds((const guint*)(Bbase + (KT) * 64 + (KH) * 32), \
      (luint*)(&Bs[BUF][KH][tid * 8]), 16, 0, 0); \
  __builtin_amdgcn_global_load_lds((const guint*)(Bbase + (size_t)128 * K + (KT) * 64 + (KH) * 32), \
      (luint*)(&Bs[BUF][KH][(tid + 512) * 8]), 16, 0, 0); \
} while (0)
#define MFMA16S(FB, A0,A1,A2,A3, B0,B1,B2,B3) \
  MROW((FB) + 0, A0, B0,B1,B2,B3) MROW((FB) + 1, A1, B0,B1,B2,B3) \
  MROW((FB) + 2, A2, B0,B1,B2,B3) MROW((FB) + 3, A3, B0,B1,B2,B3)

#define TILE4(CUR, KT, ST1, ST2, V1STR, V3STR, LD4, LGK4STR) { \
  const int cur_ = (CUR); \
  /* ph1 */ \
  MEMFENCE; \
  LDS_A(aN0,aN1,aN2,aN3, cur_, 0, 4); \
  if (ST1) { STAGE_A(cur_ ^ 1, 1, (KT) + 1); } \
  asm volatile("s_waitcnt " V1STR ::: "memory"); \
  asm volatile("s_waitcnt lgkmcnt(4)" ::: "memory"); \
  BARRIER; \
  __builtin_amdgcn_s_setprio(1); \
  MFMA16S(0, aP0,aP1,aP2,aP3, bP0,bP1,bP2,bP3); \
  __builtin_amdgcn_s_setprio(0); \
  /* ph2 */ \
  MEMFENCE; \
  LDS_A(aP0,aP1,aP2,aP3, cur_, 1, 0); \
  LDS_B(bN0,bN1,bN2,bN3, cur_, 1); \
  if (ST1) { STAGE_B(cur_ ^ 1, 1, (KT) + 1); } \
  asm volatile("s_waitcnt lgkmcnt(8)" ::: "memory"); \
  BARRIER; \
  __builtin_amdgcn_s_setprio(1); \
  MFMA16S(4, aN0,aN1,aN2,aN3, bP0,bP1,bP2,bP3); \
  __builtin_amdgcn_s_setprio(0); \
  /* ph3 */ \
  MEMFENCE; \
  LDS_A(aN0,aN1,aN2,aN3, cur_, 1, 4); \
  if (ST2) { STAGE_A(cur_, 0, (KT) + 2); } \
  asm volatile("s_waitcnt " V3STR ::: "memory"); \
  asm volatile("s_waitcnt lgkmcnt(4)" ::: "memory"); \
  BARRIER; \
  __builtin_amdgcn_s_setprio(1); \
  MFMA16S(0, aP0,aP1,aP2,aP3, bN0,bN1,bN2,bN3); \
  __builtin_amdgcn_s_setprio(0); \
  /* ph4 */ \
  MEMFENCE; \
  if (LD4) { LDS_A(aP0,aP1,aP2,aP3, cur_ ^ 1, 0, 0); \
             LDS_B(bP0,bP1,bP2,bP3, cur_ ^ 1, 0); } \
  if (ST2) { STAGE_B(cur_, 0, (KT) + 2); } \
  asm volatile("s_waitcnt " LGK4STR ::: "memory"); \
  BARRIER; \
  __builtin_amdgcn_s_setprio(1); \
  MFMA16S(4, aN0,aN1,aN2,aN3, bN0,bN1,bN2,bN3); \
  __builtin_amdgcn_s_setprio(0); \
}

template <bool BIAS, bool RELU, bool RESID, bool OBF16>
__global__ __launch_bounds__(512, 2) void gemm8(
    const u16* __restrict__ A, const u16* __restrict__ BT,
    const float* __restrict__ bias, const float* __restrict__ resid,
    void* __restrict__ Cv, int M, int N, int K) {
  __shared__ u16 As[2][2][8192];
  __shared__ u16 Bs[2][2][8192];
  const int tid = threadIdx.x;
  const int lane = tid & 63, wave = tid >> 6;
  const int wm = wave >> 2, wn = wave & 3;
  const int nwg = gridDim.x;
  const int bid = blockIdx.x;
  const int wg = ((nwg & 7) == 0) ? ((bid & 7) * (nwg >> 3) + (bid >> 3)) : bid;
  const int nmt = M >> 8;
  const int m0 = (wg % nmt) * 256;
  const int n0 = (wg / nmt) * 256;
  const int NT = K >> 6;
  const int sr = tid >> 2;
  const int ssc = (((tid & 3) ^ ((tid >> 3) & 3)) * 8);  // pre-swizzled chunk
  const u16* Abase = A + (size_t)(m0 + sr) * K + ssc;
  const u16* Bbase = BT + (size_t)(n0 + sr) * K + ssc;
  const int rg = (((lane >> 4) ^ ((lane >> 1) & 3)) * 8);  // read-chunk XOR

  f32x4 acc[8][4] = {};
  short8v aP0, aP1, aP2, aP3, aN0, aN1, aN2, aN3;
  short8v bP0, bP1, bP2, bP3, bN0, bN1, bN2, bN3;

  STAGE_A(0, 0, 0); STAGE_B(0, 0, 0);
  STAGE_A(0, 1, 0); STAGE_B(0, 1, 0);
  STAGE_A(1, 0, 1); STAGE_B(1, 0, 1);
  asm volatile("s_waitcnt vmcnt(8)" ::: "memory");
  BARRIER;
  MEMFENCE;
  LDS_A(aP0,aP1,aP2,aP3, 0, 0, 0);
  LDS_B(bP0,bP1,bP2,bP3, 0, 0);

  int kt = 0;
  for (; kt < NT - 2; ++kt) {
    TILE4(kt & 1, kt, true, true, "vmcnt(6)", "vmcnt(6)", true, "lgkmcnt(8)");
  }
  TILE4(kt & 1, kt, true, false, "vmcnt(6)", "vmcnt(4)", true, "lgkmcnt(8)");
  ++kt;
  TILE4(kt & 1, kt, false, false, "vmcnt(0)", "vmcnt(0)", false, "lgkmcnt(0)");

  #pragma unroll
  for (int f = 0; f < 8; ++f) {
    #pragma unroll
    for (int n = 0; n < 4; ++n) {
      const int col = n0 + wn * 64 + n * 16 + (lane & 15);
      #pragma unroll
      for (int r = 0; r < 4; ++r) {
        const int row = m0 + wm * 128 + f * 16 + (lane >> 4) * 4 + r;
        float v = acc[f][n][r];
        if (BIAS) v += bias[col];
        if (RELU) v = fmaxf(v, 0.f);
        if (RESID) v += resid[(size_t)row * N + col];
        if (OBF16)
          ((u16*)Cv)[(size_t)row * N + col] = f2bf(v);
        else
          ((float*)Cv)[(size_t)row * N + col] = v;
      }
    }
  }
}

// ===========================================================================
// gemm4p: 128x128 tile, 4 waves (2x2), R6 pipeline halved; ~2 blocks/CU.
// Used for proj (K=1024) and MLP2 (K=4096).
// ===========================================================================
#define LDA4_(BUF, KH, F) \
  (*(const short8v*)&As[BUF][KH][(wm * 64 + (F) * 16 + (lane & 15)) * 32 + rg])
#define LDB4_(BUF, KH, NF) \
  (*(const short8v*)&Bs[BUF][KH][(wn * 64 + (NF) * 16 + (lane & 15)) * 32 + rg])
#define STAGE_A4(BUF, KH, KT) do { \
  __builtin_amdgcn_global_load_lds((const guint*)(Abase + (KT) * 64 + (KH) * 32), \
      (luint*)(&As[BUF][KH][tid * 8]), 16, 0, 0); \
  __builtin_amdgcn_global_load_lds((const guint*)(Abase + (size_t)64 * K + (KT) * 64 + (KH) * 32), \
      (luint*)(&As[BUF][KH][(tid + 256) * 8]), 16, 0, 0); \
} while (0)
#define STAGE_B4(BUF, KH, KT) do { \
  __builtin_amdgcn_global_load_lds((const guint*)(Bbase + (KT) * 64 + (KH) * 32), \
      (luint*)(&Bs[BUF][KH][tid * 8]), 16, 0, 0); \
  __builtin_amdgcn_global_load_lds((const guint*)(Bbase + (size_t)64 * K + (KT) * 64 + (KH) * 32), \
      (luint*)(&Bs[BUF][KH][(tid + 256) * 8]), 16, 0, 0); \
} while (0)
#define MFMA8S(F0, F1, A0, A1, B0,B1,B2,B3) \
  MROW(F0, A0, B0,B1,B2,B3) MROW(F1, A1, B0,B1,B2,B3)

#define TILE4P(CUR, KT, ST1, ST2, V1STR, V3STR, LD4, LGK4STR) { \
  const int cur_ = (CUR); \
  MEMFENCE; \
  aN0 = LDA4_(cur_, 0, 2); aN1 = LDA4_(cur_, 0, 3); \
  if (ST1) { STAGE_A4(cur_ ^ 1, 1, (KT) + 1); } \
  asm volatile("s_waitcnt " V1STR ::: "memory"); \
  asm volatile("s_waitcnt lgkmcnt(2)" ::: "memory"); \
  BARRIER; \
  __builtin_amdgcn_s_setprio(1); \
  MFMA8S(0, 1, aP0, aP1, bP0,bP1,bP2,bP3); \
  __builtin_amdgcn_s_setprio(0); \
  MEMFENCE; \
  aP0 = LDA4_(cur_, 1, 0); aP1 = LDA4_(cur_, 1, 1); \
  bN0 = LDB4_(cur_, 1, 0); bN1 = LDB4_(cur_, 1, 1); \
  bN2 = LDB4_(cur_, 1, 2); bN3 = LDB4_(cur_, 1, 3); \
  if (ST1) { STAGE_B4(cur_ ^ 1, 1, (KT) + 1); } \
  asm volatile("s_waitcnt lgkmcnt(6)" ::: "memory"); \
  BARRIER; \
  __builtin_amdgcn_s_setprio(1); \
  MFMA8S(2, 3, aN0, aN1, bP0,bP1,bP2,bP3); \
  __builtin_amdgcn_s_setprio(0); \
  MEMFENCE; \
  aN0 = LDA4_(cur_, 1, 2); aN1 = LDA4_(cur_, 1, 3); \
  if (ST2) { STAGE_A4(cur_, 0, (KT) + 2); } \
  asm volatile("s_waitcnt " V3STR ::: "memory"); \
  asm volatile("s_waitcnt lgkmcnt(2)" ::: "memory"); \
  BARRIER; \
  __builtin_amdgcn_s_setprio(1); \
  MFMA8S(0, 1, aP0, aP1, bN0,bN1,bN2,bN3); \
  __builtin_amdgcn_s_setprio(0); \
  MEMFENCE; \
  if (LD4) { aP0 = LDA4_(cur_ ^ 1, 0, 0); aP1 = LDA4_(cur_ ^ 1, 0, 1); \
             bP0 = LDB4_(cur_ ^ 1, 0, 0); bP1 = LDB4_(cur_ ^ 1, 0, 1); \
             bP2 = LDB4_(cur_ ^ 1, 0, 2); bP3 = LDB4_(cur_ ^ 1, 0, 3); } \
  if (ST2) { STAGE_B4(cur_, 0, (KT) + 2); } \
  asm volatile("s_waitcnt " LGK4STR ::: "memory"); \
  BARRIER; \
  __builtin_amdgcn_s_setprio(1); \
  MFMA8S(2, 3, aN0, aN1, bN0,bN1,bN2,bN3); \
  __builtin_amdgcn_s_setprio(0); \
}

template <bool BIAS, bool RELU, bool RESID, bool OBF16>
__global__ __launch_bounds__(256, 2) void gemm4p(
    const u16* __restrict__ A, const u16* __restrict__ BT,
    const float* __restrict__ bias, const float* __restrict__ resid,
    void* __restrict__ Cv, int M, int N, int K) {
  __shared__ u16 As[2][2][4096];
  __shared__ u16 Bs[2][2][4096];
  const int tid = threadIdx.x;
  const int lane = tid & 63, wave = tid >> 6;
  const int wm = wave >> 1, wn = wave & 1;
  const int m0 = blockIdx.x * 128, n0 = blockIdx.y * 128;
  const int NT = K >> 6;
  const int sr = tid >> 2;
  const int ssc = (((tid & 3) ^ ((tid >> 3) & 3)) * 8);  // pre-swizzled chunk
  const u16* Abase = A + (size_t)(m0 + sr) * K + ssc;
  const u16* Bbase = BT + (size_t)(n0 + sr) * K + ssc;
  const int rg = (((lane >> 4) ^ ((lane >> 1) & 3)) * 8);

  f32x4 acc[4][4] = {};
  short8v aP0, aP1, aN0, aN1;
  short8v bP0, bP1, bP2, bP3, bN0, bN1, bN2, bN3;

  STAGE_A4(0, 0, 0); STAGE_B4(0, 0, 0);
  STAGE_A4(0, 1, 0); STAGE_B4(0, 1, 0);
  STAGE_A4(1, 0, 1); STAGE_B4(1, 0, 1);
  asm volatile("s_waitcnt vmcnt(8)" ::: "memory");
  BARRIER;
  MEMFENCE;
  aP0 = LDA4_(0, 0, 0); aP1 = LDA4_(0, 0, 1);
  bP0 = LDB4_(0, 0, 0); bP1 = LDB4_(0, 0, 1);
  bP2 = LDB4_(0, 0, 2); bP3 = LDB4_(0, 0, 3);

  int kt = 0;
  for (; kt < NT - 2; ++kt) {
    TILE4P(kt & 1, kt, true, true, "vmcnt(6)", "vmcnt(6)", true, "lgkmcnt(6)");
  }
  TILE4P(kt & 1, kt, true, false, "vmcnt(6)", "vmcnt(4)", true, "lgkmcnt(6)");
  ++kt;
  TILE4P(kt & 1, kt, false, false, "vmcnt(0)", "vmcnt(0)", false, "lgkmcnt(0)");

  #pragma unroll
  for (int f = 0; f < 4; ++f) {
    #pragma unroll
    for (int n = 0; n < 4; ++n) {
      const int col = n0 + wn * 64 + n * 16 + (lane & 15);
      #pragma unroll
      for (int r = 0; r < 4; ++r) {
        const int row = m0 + wm * 64 + f * 16 + (lane >> 4) * 4 + r;
        float v = acc[f][n][r];
        if (BIAS) v += bias[col];
        if (RELU) v = fmaxf(v, 0.f);
        if (RESID) v += resid[(size_t)row * N + col];
        if (OBF16)
          ((u16*)Cv)[(size_t)row * N + col] = f2bf(v);
        else
          ((float*)Cv)[(size_t)row * N + col] = v;
      }
    }
  }
}

// ---------------------------------------------------------------------------
// Fallback fp32 GEMM for LM head (A bf16, B fp32 [K][N], +bias)
// ---------------------------------------------------------------------------
__global__ __launch_bounds__(256) void gemm_fb(
    const u16* __restrict__ A, const float* __restrict__ B,
    const float* __restrict__ bias, float* __restrict__ C, int M, int N, int K) {
  __shared__ alignas(16) float Asm[16][68];
  __shared__ alignas(16) float Bsm[16][68];
  const int tid = threadIdx.x;
  const int tx = tid & 15, ty = tid >> 4;
  const int m0 = blockIdx.y * 64, n0 = blockIdx.x * 64;
  const int ar = tid >> 2, ac = (tid & 3) * 4;
  const int br = tid >> 4, bc = (tid & 15) * 4;
  float acc[4][4] = {};
  for (int k0 = 0; k0 < K; k0 += 16) {
    ushort4 au = *(const ushort4*)(A + (size_t)(m0 + ar) * K + k0 + ac);
    float4 bv = *(const float4*)(B + (size_t)(k0 + br) * N + n0 + bc);
    Asm[ac + 0][ar] = bf2f_lo(au.x);
    Asm[ac + 1][ar] = bf2f_lo(au.y);
    Asm[ac + 2][ar] = bf2f_lo(au.z);
    Asm[ac + 3][ar] = bf2f_lo(au.w);
    *(float4*)&Bsm[br][bc] = bv;
    __syncthreads();
    #pragma unroll
    for (int kk = 0; kk < 16; ++kk) {
      float4 a = *(const float4*)&Asm[kk][ty * 4];
      float4 b = *(const float4*)&Bsm[kk][tx * 4];
      acc[0][0] += a.x * b.x; acc[0][1] += a.x * b.y; acc[0][2] += a.x * b.z; acc[0][3] += a.x * b.w;
      acc[1][0] += a.y * b.x; acc[1][1] += a.y * b.y; acc[1][2] += a.y * b.z; acc[1][3] += a.y * b.w;
      acc[2][0] += a.z * b.x; acc[2][1] += a.z * b.y; acc[2][2] += a.z * b.z; acc[2][3] += a.z * b.w;
      acc[3][0] += a.w * b.x; acc[3][1] += a.w * b.y; acc[3][2] += a.w * b.z; acc[3][3] += a.w * b.w;
    }
    __syncthreads();
  }
  #pragma unroll
  for (int i = 0; i < 4; ++i) {
    const int m = m0 + ty * 4 + i;
    #pragma unroll
    for (int j = 0; j < 4; ++j) {
      const int n = n0 + tx * 4 + j;
      C[(size_t)m * N + n] = acc[i][j] + bias[n];
    }
  }
}

// ---------------------------------------------------------------------------
// MFMA flash attention — 8 waves, 128 q-rows/block, KB=64.
// qkv rows of 3072: [0..1023]=Q, [1024..2047]=K, [2048..3071]=V.
// vt: [h*64+e][b*S+s] bf16 (stride MM), from transpose_v.
// Heaviest q-tiles first; per-wave-uniform 'active' guard (barriers uniform).
// ---------------------------------------------------------------------------
__global__ __launch_bounds__(512) void attn_mfma(
    const u16* __restrict__ qkv, const u16* __restrict__ vt,
    u16* __restrict__ o) {
  __shared__ alignas(16) u16 Ksh[64 * 64];
  __shared__ alignas(16) u16 Vsh[64 * 64];
  __shared__ unsigned Plds[8][16 * 41];
  __shared__ float bcast[8][16];
  const int tid = threadIdx.x;
  const int lane = tid & 63, wave = tid >> 6;
  const int g = lane >> 4, qi = lane & 15;
  const int qt = (SS / 128 - 1) - blockIdx.x;   // heaviest first
  const int h = blockIdx.y, b = blockIdx.z;
  const int q0w = qt * 128 + wave * 16;
  const int ktmax = 2 * qt + 1;

  short8v qf0, qf1;
  {
    const u16* qp = qkv + ((size_t)b * SS + q0w + qi) * 3072 + h * DHH + g * 8;
    qf0 = *(const short8v*)qp;
    qf1 = *(const short8v*)(qp + 32);
  }

  f32x4 oacc[4] = {};
  float mrow = -1e30f, lrow = 0.f;

  for (int kt = 0; kt <= ktmax; ++kt) {
    __syncthreads();
    {
      const int row = tid >> 3, ch = tid & 7;
      const int sch = ch ^ (row & 7);
      __builtin_amdgcn_global_load_lds(
          (const guint*)(qkv + ((size_t)b * SS + kt * 64 + row) * 3072 + 1024 + h * DHH + sch * 8),
          (luint*)(Ksh + tid * 8), 16, 0, 0);
      __builtin_amdgcn_global_load_lds(
          (const guint*)(vt + ((size_t)(h * DHH + row)) * MM + b * SS + kt * 64 + sch * 8),
          (luint*)(Vsh + tid * 8), 16, 0, 0);
    }
    __syncthreads();

    const bool active = (kt * 64 <= q0w + 15);
    if (active) {
      f32x4 st[4] = {};
      #pragma unroll
      for (int t = 0; t < 4; ++t) {
        const int row = t * 16 + qi;
        const int swz = (row & 7) << 4;
        short8v kf0 = *(const short8v*)(Ksh + row * 64 + (((g * 16) ^ swz) >> 1));
        short8v kf1 = *(const short8v*)(Ksh + row * 64 + (((64 + g * 16) ^ swz) >> 1));
        st[t] = __builtin_amdgcn_mfma_f32_16x16x32_bf16(kf0, qf0, st[t], 0, 0, 0);
        st[t] = __builtin_amdgcn_mfma_f32_16x16x32_bf16(kf1, qf1, st[t], 0, 0, 0);
      }

      const int diag = q0w + qi - kt * 64;
      if (diag < 63) {
        #pragma unroll
        for (int t = 0; t < 4; ++t)
          #pragma unroll
          for (int r = 0; r < 4; ++r)
            if (t * 16 + 4 * g + r > diag) st[t][r] = -1e30f;
      }

      float mt = st[0][0];
      #pragma unroll
      for (int t = 0; t < 4; ++t)
        #pragma unroll
        for (int r = 0; r < 4; ++r) mt = fmaxf(mt, st[t][r]);
      mt = fmaxf(mt, __shfl_xor(mt, 16));
      mt = fmaxf(mt, __shfl_xor(mt, 32));
      const float mnew = fmaxf(mrow, mt * 0.125f);
      const float corr = __expf(mrow - mnew);
      float pl = 0.f;
      #pragma unroll
      for (int t = 0; t < 4; ++t) {
        #pragma unroll
        for (int r2 = 0; r2 < 2; ++r2) {
          float plo = __expf(fmaf(st[t][2 * r2], 0.125f, -mnew));
          float phi = __expf(fmaf(st[t][2 * r2 + 1], 0.125f, -mnew));
          pl += plo + phi;
          Plds[wave][qi * 41 + 8 * t + 2 * g + r2] =
              (unsigned)f2bf(plo) | ((unsigned)f2bf(phi) << 16);
        }
      }
      pl += __shfl_xor(pl, 16);
      pl += __shfl_xor(pl, 32);
      lrow = lrow * corr + pl;
      mrow = mnew;

      if (g == 0) bcast[wave][qi] = corr;
      float c0 = bcast[wave][g * 4 + 0];
      float c1 = bcast[wave][g * 4 + 1];
      float c2 = bcast[wave][g * 4 + 2];
      float c3 = bcast[wave][g * 4 + 3];
      #pragma unroll
      for (int dvt = 0; dvt < 4; ++dvt) {
        oacc[dvt][0] *= c0; oacc[dvt][1] *= c1;
        oacc[dvt][2] *= c2; oacc[dvt][3] *= c3;
      }

      union U8 { unsigned u[4]; short8v s8; };
      U8 pa0, pa1;
      #pragma unroll
      for (int c = 0; c < 4; ++c) {
        pa0.u[c] = Plds[wave][qi * 41 + g * 4 + c];
        pa1.u[c] = Plds[wave][qi * 41 + 16 + g * 4 + c];
      }
      #pragma unroll
      for (int dvt = 0; dvt < 4; ++dvt) {
        const int row = dvt * 16 + qi;
        const int swz = (row & 7) << 4;
        short8v v0 = *(const short8v*)(Vsh + row * 64 + (((g * 16) ^ swz) >> 1));
        short8v v1 = *(const short8v*)(Vsh + row * 64 + (((64 + g * 16) ^ swz) >> 1));
        oacc[dvt] = __builtin_amdgcn_mfma_f32_16x16x32_bf16(pa0.s8, v0, oacc[dvt], 0, 0, 0);
        oacc[dvt] = __builtin_amdgcn_mfma_f32_16x16x32_bf16(pa1.s8, v1, oacc[dvt], 0, 0, 0);
      }
    }
  }

  if (g == 0) bcast[wave][qi] = 1.f / lrow;
  float i0 = bcast[wave][g * 4 + 0];
  float i1 = bcast[wave][g * 4 + 1];
  float i2 = bcast[wave][g * 4 + 2];
  float i3 = bcast[wave][g * 4 + 3];
  #pragma unroll
  for (int dvt = 0; dvt < 4; ++dvt) {
    const int col = h * DHH + dvt * 16 + qi;
    o[((size_t)b * SS + q0w + g * 4 + 0) * DD + col] = f2bf(oacc[dvt][0] * i0);
    o[((size_t)b * SS + q0w + g * 4 + 1) * DD + col] = f2bf(oacc[dvt][1] * i1);
    o[((size_t)b * SS + q0w + g * 4 + 2) * DD + col] = f2bf(oacc[dvt][2] * i2);
    o[((size_t)b * SS + q0w + g * 4 + 3) * DD + col] = f2bf(oacc[dvt][3] * i3);
  }
}

// ---------------------------------------------------------------------------
extern "C" void kernel_launch(void* const* d_in, const int* in_sizes, int n_in,
                              void* d_out, int out_size, void* d_ws, size_t ws_size,
                              hipStream_t stream) {
  const int* idx = (const int*)d_in[0];
  const float* tok_emb = (const float*)d_in[1];
  const float* pos_emb = (const float*)d_in[2];
  const float* ln1_s = (const float*)d_in[3];
  const float* ln1_b = (const float*)d_in[4];
  const float* wq = (const float*)d_in[5];
  const float* wk = (const float*)d_in[6];
  const float* wv = (const float*)d_in[7];
  const float* wproj = (const float*)d_in[8];
  const float* ln2_s = (const float*)d_in[9];
  const float* ln2_b = (const float*)d_in[10];
  const float* w1 = (const float*)d_in[11];
  const float* b1 = (const float*)d_in[12];
  const float* w2 = (const float*)d_in[13];
  const float* b2 = (const float*)d_in[14];
  const float* lnf_s = (const float*)d_in[15];
  const float* lnf_b = (const float*)d_in[16];
  const float* lm_w = (const float*)d_in[17];
  const float* lm_b = (const float*)d_in[18];

  const size_t MD = (size_t)MM * DD;

  // d_out scratch (all dead before the LM GEMM writes d_out)
  u16* sc0 = (u16*)d_out;
  u16* BTqkv = sc0;                                  // LL x [3072][1024]
  u16* BTp = BTqkv + (size_t)LL * 3072 * DD;
  u16* BTw1 = BTp + (size_t)LL * DD * DD;
  u16* BTw2 = BTw1 + (size_t)LL * DD * 4 * DD;
  u16* qkvb = BTw2 + (size_t)LL * DD * 4 * DD;       // [M][3072]
  u16* vtb = qkvb + (size_t)MM * 3072;               // [1024][4096]
  u16* ob = vtb + MD;
  u16* tmp = ob + MD;                                // [M][4096]

  // d_ws: x fp32 (16MB) + h bf16 (8MB) + BT(lm_w) bf16 (65.5MB) if room
  float* x = (float*)d_ws;
  u16* h = (u16*)((char*)d_ws + MD * 4);
  u16* BTlm = (u16*)((char*)d_ws + MD * 4 + MD * 2);
  const bool big_ws = ws_size >= (MD * 4 + MD * 2 + (size_t)VV * DD * 2);

  const dim3 blk(256);

  convT_kernel<true><<<dim3(DD / 32, DD / 64, LL), blk, 0, stream>>>(
      wq, BTqkv, DD, DD, (size_t)3072 * DD);
  convT_kernel<true><<<dim3(DD / 32, DD / 64, LL), blk, 0, stream>>>(
      wk, BTqkv + (size_t)DD * DD, DD, DD, (size_t)3072 * DD);
  convT_kernel<true><<<dim3(DD / 32, DD / 64, LL), blk, 0, stream>>>(
      wv, BTqkv + (size_t)2 * DD * DD, DD, DD, (size_t)3072 * DD);
  convT_kernel<false><<<dim3(DD / 32, DD / 64, LL), blk, 0, stream>>>(
      wproj, BTp, DD, DD, (size_t)DD * DD);
  convT_kernel<false><<<dim3(4 * DD / 32, DD / 64, LL), blk, 0, stream>>>(
      w1, BTw1, DD, 4 * DD, (size_t)DD * 4 * DD);
  convT_kernel<false><<<dim3(DD / 32, 4 * DD / 64, LL), blk, 0, stream>>>(
      w2, BTw2, 4 * DD, DD, (size_t)4 * DD * DD);
  if (big_ws)
    convT_kernel<false><<<dim3(VV / 32, DD / 64, 1), blk, 0, stream>>>(
        lm_w, BTlm, DD, VV, (size_t)VV * DD);

  embed_kernel<<<(MM * DD / 4 + 255) / 256, blk, 0, stream>>>(idx, tok_emb, pos_emb, x);

  for (int l = 0; l < LL; ++l) {
    ln_bf16_kernel<<<MM, blk, 0, stream>>>(x, ln1_s + l * DD, ln1_b + l * DD, h);
    // Fused Q+K+V (gemm8 256^2): C = h @ [Wq|Wk|Wv], N=3072
    gemm8<false, false, false, true><<<dim3((MM / 256) * (3072 / 256)), dim3(512), 0, stream>>>(
        h, BTqkv + (size_t)l * 3072 * DD, nullptr, nullptr, qkvb, MM, 3072, DD);
    transpose_v<<<dim3(MM / 32, DD / 32), blk, 0, stream>>>(qkvb, vtb);
    attn_mfma<<<dim3(SS / 128, HH, BB), dim3(512), 0, stream>>>(qkvb, vtb, ob);
    // Projection + residual (gemm4p 128^2)
    gemm4p<false, false, true, false><<<dim3(MM / 128, DD / 128), blk, 0, stream>>>(
        ob, BTp + (size_t)l * DD * DD, nullptr, x, x, MM, DD, DD);
    ln_bf16_kernel<<<MM, blk, 0, stream>>>(x, ln2_s + l * DD, ln2_b + l * DD, h);
    // MLP1 (gemm8 256^2)
    gemm8<true, true, false, true><<<dim3((MM / 256) * (4 * DD / 256)), dim3(512), 0, stream>>>(
        h, BTw1 + (size_t)l * DD * 4 * DD, b1 + (size_t)l * 4 * DD, nullptr, tmp,
        MM, 4 * DD, DD);
    // MLP2 + residual (gemm4p 128^2)
    gemm4p<true, false, true, false><<<dim3(MM / 128, DD / 128), blk, 0, stream>>>(
        tmp, BTw2 + (size_t)l * 4 * DD * DD, b2 + (size_t)l * DD, x, x, MM, DD, 4 * DD);
  }

  ln_bf16_kernel<<<MM, blk, 0, stream>>>(x, lnf_s, lnf_b, h);
  if (big_ws) {
    // LM head (gemm8 256^2)
    gemm8<true, false, false, false><<<dim3((MM / 256) * (VV / 256)), dim3(512), 0, stream>>>(
        h, BTlm, lm_b, nullptr, (float*)d_out, MM, VV, DD);
  } else {
    gemm_fb<<<dim3(VV / 64, MM / 64), blk, 0, stream>>>(
        h, lm_w, lm_b, (float*)d_out, MM, VV, DD);
  }
}

// Round 15
// 2349.025 us; speedup vs baseline: 1.0770x; 1.0202x over previous
//
#include <hip/hip_runtime.h>
#include <hip/hip_bf16.h>

// Model dims (fixed by reference)
#define LL 8
#define DD 1024
#define HH 16
#define DHH 64
#define SS 1024
#define BB 4
#define VV 32000
#define MM (BB * SS)   // 4096 rows

typedef unsigned short u16;
typedef __attribute__((ext_vector_type(8))) short short8v;   // 8 bf16 (4 VGPRs)
typedef __attribute__((ext_vector_type(4))) float f32x4;
typedef unsigned int __attribute__((address_space(1))) guint;
typedef unsigned int __attribute__((address_space(3))) luint;

__device__ __forceinline__ float bf2f_lo(unsigned u) { return __uint_as_float(u << 16); }
__device__ __forceinline__ u16 f2bf(float f) {
  unsigned x = __float_as_uint(f);
  return (u16)((x + 0x7fffu + ((x >> 16) & 1u)) >> 16);
}

// ---------------------------------------------------------------------------
// Embedding
// ---------------------------------------------------------------------------
__global__ __launch_bounds__(256) void embed_kernel(
    const int* __restrict__ idx, const float* __restrict__ tok,
    const float* __restrict__ pos, float* __restrict__ x) {
  int i = blockIdx.x * blockDim.x + threadIdx.x;
  int elem = i * 4;
  int row = elem / DD;
  int d = elem % DD;
  int s = row % SS;
  int t = idx[row];
  float4 tv = *(const float4*)(tok + (size_t)t * DD + d);
  float4 pv = *(const float4*)(pos + (size_t)s * DD + d);
  tv.x += pv.x; tv.y += pv.y; tv.z += pv.z; tv.w += pv.w;
  *(float4*)(x + (size_t)elem) = tv;
}

// ---------------------------------------------------------------------------
// LayerNorm over D=1024 (fp32 in, bf16 out)
// ---------------------------------------------------------------------------
__global__ __launch_bounds__(256) void ln_bf16_kernel(
    const float* __restrict__ x, const float* __restrict__ sc,
    const float* __restrict__ bi, u16* __restrict__ out) {
  const int row = blockIdx.x;
  const int tid = threadIdx.x;
  __shared__ float red[4];
  float4 v = ((const float4*)(x + (size_t)row * DD))[tid];
  float s = v.x + v.y + v.z + v.w;
  #pragma unroll
  for (int off = 32; off; off >>= 1) s += __shfl_down(s, off);
  if ((tid & 63) == 0) red[tid >> 6] = s;
  __syncthreads();
  float mean = (red[0] + red[1] + red[2] + red[3]) * (1.f / DD);
  float dx = v.x - mean, dy = v.y - mean, dz = v.z - mean, dw = v.w - mean;
  float vs = dx * dx + dy * dy + dz * dz + dw * dw;
  __syncthreads();
  #pragma unroll
  for (int off = 32; off; off >>= 1) vs += __shfl_down(vs, off);
  if ((tid & 63) == 0) red[tid >> 6] = vs;
  __syncthreads();
  float var = (red[0] + red[1] + red[2] + red[3]) * (1.f / DD);
  float rstd = rsqrtf(var + 1e-5f);
  float4 s4 = ((const float4*)sc)[tid];
  float4 b4 = ((const float4*)bi)[tid];
  ushort4 o;
  o.x = f2bf(dx * rstd * s4.x + b4.x);
  o.y = f2bf(dy * rstd * s4.y + b4.y);
  o.z = f2bf(dz * rstd * s4.z + b4.z);
  o.w = f2bf(dw * rstd * s4.w + b4.w);
  *(ushort4*)(out + (size_t)row * DD + tid * 4) = o;
}

// ---------------------------------------------------------------------------
// Weight transpose + fp32->bf16: W [l][K][N] (or head-blocked) -> BT rows [N][K]
// 64k x 32n tiles; ushort2 stores.
// ---------------------------------------------------------------------------
template <bool HEADW>
__global__ __launch_bounds__(256) void convT_kernel(
    const float* __restrict__ W, u16* __restrict__ BT, int K, int N,
    size_t lstride) {
  __shared__ float tile[64][33];
  const int n0 = blockIdx.x * 32, k0 = blockIdx.y * 64, l = blockIdx.z;
  const int tx = threadIdx.x & 31, ty = threadIdx.x >> 5;
  const float* Wl;
  int ld;
  if (HEADW) {
    const int h = n0 >> 6;
    Wl = W + ((size_t)(l * HH + h) * K) * 64 + (n0 & 63);
    ld = 64;
  } else {
    Wl = W + (size_t)l * K * N + n0;
    ld = N;
  }
  #pragma unroll
  for (int i = 0; i < 8; ++i)
    tile[ty + 8 * i][tx] = Wl[(size_t)(k0 + ty + 8 * i) * ld + tx];
  __syncthreads();
  u16* out = BT + (size_t)l * lstride;
  const int kk = tx * 2;
  #pragma unroll
  for (int j = 0; j < 4; ++j) {
    const int nn = ty + 8 * j;
    ushort2 v;
    v.x = f2bf(tile[kk + 0][nn]);
    v.y = f2bf(tile[kk + 1][nn]);
    *(ushort2*)(out + (size_t)(n0 + nn) * K + k0 + kk) = v;
  }
}

// ---------------------------------------------------------------------------
// V transpose: vt[dv][s] = qkv[s][2048+dv]  (bf16, 32x32 tiles)
// ---------------------------------------------------------------------------
__global__ __launch_bounds__(256) void transpose_v(
    const u16* __restrict__ qkv, u16* __restrict__ vt) {
  __shared__ u16 t[32][33];
  const int s0 = blockIdx.x * 32, d0 = blockIdx.y * 32;
  const int tx = threadIdx.x & 31, ty = threadIdx.x >> 5;
  #pragma unroll
  for (int i = 0; i < 4; ++i)
    t[ty + 8 * i][tx] = qkv[(size_t)(s0 + ty + 8 * i) * 3072 + 2048 + d0 + tx];
  __syncthreads();
  #pragma unroll
  for (int i = 0; i < 4; ++i)
    vt[(size_t)(d0 + ty + 8 * i) * MM + s0 + tx] = t[tx][ty + 8 * i];
}

// ===========================================================================
// Shared schedule macros
// ===========================================================================
#define BARRIER __builtin_amdgcn_s_barrier()
#define MEMFENCE asm volatile("" ::: "memory")
#define MROW(F, AQ, B0,B1,B2,B3) \
  acc[F][0] = __builtin_amdgcn_mfma_f32_16x16x32_bf16(AQ, B0, acc[F][0], 0, 0, 0); \
  acc[F][1] = __builtin_amdgcn_mfma_f32_16x16x32_bf16(AQ, B1, acc[F][1], 0, 0, 0); \
  acc[F][2] = __builtin_amdgcn_mfma_f32_16x16x32_bf16(AQ, B2, acc[F][2], 0, 0, 0); \
  acc[F][3] = __builtin_amdgcn_mfma_f32_16x16x32_bf16(AQ, B3, acc[F][3], 0, 0, 0);

// ===========================================================================
// gemm8: 256x256 tile, 8 waves, register-double-buffered 4-phase pipeline
// (R6-verified).  NTC: LDS-bounce epilogue + nontemporal row-contiguous
// f32x4 stores (LM head only — keeps A/B L3-resident).
// ===========================================================================
#define LDA_(BUF, KH, F) \
  (*(const short8v*)&As[BUF][KH][(wm * 128 + (F) * 16 + (lane & 15)) * 32 + rg])
#define LDB_(BUF, KH, NF) \
  (*(const short8v*)&Bs[BUF][KH][(wn * 64 + (NF) * 16 + (lane & 15)) * 32 + rg])
#define LDS_A(S0,S1,S2,S3, BUF, KH, FB) { \
  S0 = LDA_(BUF, KH, (FB) + 0); S1 = LDA_(BUF, KH, (FB) + 1); \
  S2 = LDA_(BUF, KH, (FB) + 2); S3 = LDA_(BUF, KH, (FB) + 3); }
#define LDS_B(S0,S1,S2,S3, BUF, KH) { \
  S0 = LDB_(BUF, KH, 0); S1 = LDB_(BUF, KH, 1); \
  S2 = LDB_(BUF, KH, 2); S3 = LDB_(BUF, KH, 3); }
#define STAGE_A(BUF, KH, KT) do { \
  __builtin_amdgcn_global_load_lds((const guint*)(Abase + (KT) * 64 + (KH) * 32), \
      (luint*)(&As[BUF][KH][tid * 8]), 16, 0, 0); \
  __builtin_amdgcn_global_load_lds((const guint*)(Abase + (size_t)128 * K + (KT) * 64 + (KH) * 32), \
      (luint*)(&As[BUF][KH][(tid + 512) * 8]), 16, 0, 0); \
} while (0)
#define STAGE_B(BUF, KH, KT) do { \
  __builtin_amdgcn_global_load_lds((const guint*)(Bbase + (KT) * 64 + (KH) * 32), \
      (luint*)(&Bs[BUF][KH][tid * 8]), 16, 0, 0); \
  __builtin_amdgcn_global_load_lds((const guint*)(Bbase + (size_t)128 * K + (KT) * 64 + (KH) * 32), \
      (luint*)(&Bs[BUF][KH][(tid + 512) * 8]), 16, 0, 0); \
} while (0)
#define MFMA16S(FB, A0,A1,A2,A3, B0,B1,B2,B3) \
  MROW((FB) + 0, A0, B0,B1,B2,B3) MROW((FB) + 1, A1, B0,B1,B2,B3) \
  MROW((FB) + 2, A2, B0,B1,B2,B3) MROW((FB) + 3, A3, B0,B1,B2,B3)

#define TILE4(CUR, KT, ST1, ST2, V1STR, V3STR, LD4, LGK4STR) { \
  const int cur_ = (CUR); \
  /* ph1 */ \
  MEMFENCE; \
  LDS_A(aN0,aN1,aN2,aN3, cur_, 0, 4); \
  if (ST1) { STAGE_A(cur_ ^ 1, 1, (KT) + 1); } \
  asm volatile("s_waitcnt " V1STR ::: "memory"); \
  asm volatile("s_waitcnt lgkmcnt(4)" ::: "memory"); \
  BARRIER; \
  __builtin_amdgcn_s_setprio(1); \
  MFMA16S(0, aP0,aP1,aP2,aP3, bP0,bP1,bP2,bP3); \
  __builtin_amdgcn_s_setprio(0); \
  /* ph2 */ \
  MEMFENCE; \
  LDS_A(aP0,aP1,aP2,aP3, cur_, 1, 0); \
  LDS_B(bN0,bN1,bN2,bN3, cur_, 1); \
  if (ST1) { STAGE_B(cur_ ^ 1, 1, (KT) + 1); } \
  asm volatile("s_waitcnt lgkmcnt(8)" ::: "memory"); \
  BARRIER; \
  __builtin_amdgcn_s_setprio(1); \
  MFMA16S(4, aN0,aN1,aN2,aN3, bP0,bP1,bP2,bP3); \
  __builtin_amdgcn_s_setprio(0); \
  /* ph3 */ \
  MEMFENCE; \
  LDS_A(aN0,aN1,aN2,aN3, cur_, 1, 4); \
  if (ST2) { STAGE_A(cur_, 0, (KT) + 2); } \
  asm volatile("s_waitcnt " V3STR ::: "memory"); \
  asm volatile("s_waitcnt lgkmcnt(4)" ::: "memory"); \
  BARRIER; \
  __builtin_amdgcn_s_setprio(1); \
  MFMA16S(0, aP0,aP1,aP2,aP3, bN0,bN1,bN2,bN3); \
  __builtin_amdgcn_s_setprio(0); \
  /* ph4 */ \
  MEMFENCE; \
  if (LD4) { LDS_A(aP0,aP1,aP2,aP3, cur_ ^ 1, 0, 0); \
             LDS_B(bP0,bP1,bP2,bP3, cur_ ^ 1, 0); } \
  if (ST2) { STAGE_B(cur_, 0, (KT) + 2); } \
  asm volatile("s_waitcnt " LGK4STR ::: "memory"); \
  BARRIER; \
  __builtin_amdgcn_s_setprio(1); \
  MFMA16S(4, aN0,aN1,aN2,aN3, bN0,bN1,bN2,bN3); \
  __builtin_amdgcn_s_setprio(0); \
}

template <bool BIAS, bool RELU, bool RESID, bool OBF16, bool NTC>
__global__ __launch_bounds__(512, 2) void gemm8(
    const u16* __restrict__ A, const u16* __restrict__ BT,
    const float* __restrict__ bias, const float* __restrict__ resid,
    void* __restrict__ Cv, int M, int N, int K) {
  __shared__ u16 As[2][2][8192];
  __shared__ u16 Bs[2][2][8192];
  const int tid = threadIdx.x;
  const int lane = tid & 63, wave = tid >> 6;
  const int wm = wave >> 2, wn = wave & 3;
  const int nwg = gridDim.x;
  const int bid = blockIdx.x;
  const int wg = ((nwg & 7) == 0) ? ((bid & 7) * (nwg >> 3) + (bid >> 3)) : bid;
  const int nmt = M >> 8;
  const int m0 = (wg % nmt) * 256;
  const int n0 = (wg / nmt) * 256;
  const int NT = K >> 6;
  const int sr = tid >> 2;
  const int ssc = (((tid & 3) ^ ((tid >> 3) & 3)) * 8);  // pre-swizzled chunk
  const u16* Abase = A + (size_t)(m0 + sr) * K + ssc;
  const u16* Bbase = BT + (size_t)(n0 + sr) * K + ssc;
  const int rg = (((lane >> 4) ^ ((lane >> 1) & 3)) * 8);  // read-chunk XOR

  f32x4 acc[8][4] = {};
  short8v aP0, aP1, aP2, aP3, aN0, aN1, aN2, aN3;
  short8v bP0, bP1, bP2, bP3, bN0, bN1, bN2, bN3;

  STAGE_A(0, 0, 0); STAGE_B(0, 0, 0);
  STAGE_A(0, 1, 0); STAGE_B(0, 1, 0);
  STAGE_A(1, 0, 1); STAGE_B(1, 0, 1);
  asm volatile("s_waitcnt vmcnt(8)" ::: "memory");
  BARRIER;
  MEMFENCE;
  LDS_A(aP0,aP1,aP2,aP3, 0, 0, 0);
  LDS_B(bP0,bP1,bP2,bP3, 0, 0);

  int kt = 0;
  for (; kt < NT - 2; ++kt) {
    TILE4(kt & 1, kt, true, true, "vmcnt(6)", "vmcnt(6)", true, "lgkmcnt(8)");
  }
  TILE4(kt & 1, kt, true, false, "vmcnt(6)", "vmcnt(4)", true, "lgkmcnt(8)");
  ++kt;
  TILE4(kt & 1, kt, false, false, "vmcnt(0)", "vmcnt(0)", false, "lgkmcnt(0)");

  if (NTC && !OBF16) {
    // LDS-bounce epilogue: per-wave scratch (16 rows x 68 floats),
    // NT f32x4 stores, 256B-contiguous per quarter-wave row.
    float* mysc = (float*)&As[0][0][0] + wave * (16 * 68);
    const int qi = lane & 15, g = lane >> 4;
    float bv[4];
    #pragma unroll
    for (int n = 0; n < 4; ++n)
      bv[n] = BIAS ? bias[n0 + wn * 64 + n * 16 + qi] : 0.f;
    BARRIER;  // all waves past K-loop LDS reads
    #pragma unroll
    for (int f = 0; f < 8; ++f) {
      #pragma unroll
      for (int n = 0; n < 4; ++n)
        #pragma unroll
        for (int r = 0; r < 4; ++r)
          mysc[(g * 4 + r) * 68 + n * 16 + qi] = acc[f][n][r] + bv[n];
      asm volatile("s_waitcnt lgkmcnt(0)" ::: "memory");  // wave's ds_writes done
      #pragma unroll
      for (int j = 0; j < 4; ++j) {
        const int rl = j * 4 + g;
        f32x4 v = *(f32x4*)&mysc[rl * 68 + qi * 4];
        const size_t row = (size_t)m0 + wm * 128 + f * 16 + rl;
        __builtin_nontemporal_store(
            v, (f32x4*)((float*)Cv + row * N + n0 + wn * 64 + qi * 4));
      }
      asm volatile("s_waitcnt lgkmcnt(0)" ::: "memory");  // reads done before next overwrite
    }
  } else {
    #pragma unroll
    for (int f = 0; f < 8; ++f) {
      #pragma unroll
      for (int n = 0; n < 4; ++n) {
        const int col = n0 + wn * 64 + n * 16 + (lane & 15);
        #pragma unroll
        for (int r = 0; r < 4; ++r) {
          const int row = m0 + wm * 128 + f * 16 + (lane >> 4) * 4 + r;
          float v = acc[f][n][r];
          if (BIAS) v += bias[col];
          if (RELU) v = fmaxf(v, 0.f);
          if (RESID) v += resid[(size_t)row * N + col];
          if (OBF16)
            ((u16*)Cv)[(size_t)row * N + col] = f2bf(v);
          else
            ((float*)Cv)[(size_t)row * N + col] = v;
        }
      }
    }
  }
}

// ===========================================================================
// gemm4p: 128x128 tile, 4 waves (2x2), R6 pipeline halved.
// Used for proj (K=1024) and MLP2 (K=4096).
// ===========================================================================
#define LDA4_(BUF, KH, F) \
  (*(const short8v*)&As[BUF][KH][(wm * 64 + (F) * 16 + (lane & 15)) * 32 + rg])
#define LDB4_(BUF, KH, NF) \
  (*(const short8v*)&Bs[BUF][KH][(wn * 64 + (NF) * 16 + (lane & 15)) * 32 + rg])
#define STAGE_A4(BUF, KH, KT) do { \
  __builtin_amdgcn_global_load_lds((const guint*)(Abase + (KT) * 64 + (KH) * 32), \
      (luint*)(&As[BUF][KH][tid * 8]), 16, 0, 0); \
  __builtin_amdgcn_global_load_lds((const guint*)(Abase + (size_t)64 * K + (KT) * 64 + (KH) * 32), \
      (luint*)(&As[BUF][KH][(tid + 256) * 8]), 16, 0, 0); \
} while (0)
#define STAGE_B4(BUF, KH, KT) do { \
  __builtin_amdgcn_global_load_lds((const guint*)(Bbase + (KT) * 64 + (KH) * 32), \
      (luint*)(&Bs[BUF][KH][tid * 8]), 16, 0, 0); \
  __builtin_amdgcn_global_load_lds((const guint*)(Bbase + (size_t)64 * K + (KT) * 64 + (KH) * 32), \
      (luint*)(&Bs[BUF][KH][(tid + 256) * 8]), 16, 0, 0); \
} while (0)
#define MFMA8S(F0, F1, A0, A1, B0,B1,B2,B3) \
  MROW(F0, A0, B0,B1,B2,B3) MROW(F1, A1, B0,B1,B2,B3)

#define TILE4P(CUR, KT, ST1, ST2, V1STR, V3STR, LD4, LGK4STR) { \
  const int cur_ = (CUR); \
  MEMFENCE; \
  aN0 = LDA4_(cur_, 0, 2); aN1 = LDA4_(cur_, 0, 3); \
  if (ST1) { STAGE_A4(cur_ ^ 1, 1, (KT) + 1); } \
  asm volatile("s_waitcnt " V1STR ::: "memory"); \
  asm volatile("s_waitcnt lgkmcnt(2)" ::: "memory"); \
  BARRIER; \
  __builtin_amdgcn_s_setprio(1); \
  MFMA8S(0, 1, aP0, aP1, bP0,bP1,bP2,bP3); \
  __builtin_amdgcn_s_setprio(0); \
  MEMFENCE; \
  aP0 = LDA4_(cur_, 1, 0); aP1 = LDA4_(cur_, 1, 1); \
  bN0 = LDB4_(cur_, 1, 0); bN1 = LDB4_(cur_, 1, 1); \
  bN2 = LDB4_(cur_, 1, 2); bN3 = LDB4_(cur_, 1, 3); \
  if (ST1) { STAGE_B4(cur_ ^ 1, 1, (KT) + 1); } \
  asm volatile("s_waitcnt lgkmcnt(6)" ::: "memory"); \
  BARRIER; \
  __builtin_amdgcn_s_setprio(1); \
  MFMA8S(2, 3, aN0, aN1, bP0,bP1,bP2,bP3); \
  __builtin_amdgcn_s_setprio(0); \
  MEMFENCE; \
  aN0 = LDA4_(cur_, 1, 2); aN1 = LDA4_(cur_, 1, 3); \
  if (ST2) { STAGE_A4(cur_, 0, (KT) + 2); } \
  asm volatile("s_waitcnt " V3STR ::: "memory"); \
  asm volatile("s_waitcnt lgkmcnt(2)" ::: "memory"); \
  BARRIER; \
  __builtin_amdgcn_s_setprio(1); \
  MFMA8S(0, 1, aP0, aP1, bN0,bN1,bN2,bN3); \
  __builtin_amdgcn_s_setprio(0); \
  MEMFENCE; \
  if (LD4) { aP0 = LDA4_(cur_ ^ 1, 0, 0); aP1 = LDA4_(cur_ ^ 1, 0, 1); \
             bP0 = LDB4_(cur_ ^ 1, 0, 0); bP1 = LDB4_(cur_ ^ 1, 0, 1); \
             bP2 = LDB4_(cur_ ^ 1, 0, 2); bP3 = LDB4_(cur_ ^ 1, 0, 3); } \
  if (ST2) { STAGE_B4(cur_, 0, (KT) + 2); } \
  asm volatile("s_waitcnt " LGK4STR ::: "memory"); \
  BARRIER; \
  __builtin_amdgcn_s_setprio(1); \
  MFMA8S(2, 3, aN0, aN1, bN0,bN1,bN2,bN3); \
  __builtin_amdgcn_s_setprio(0); \
}

template <bool BIAS, bool RELU, bool RESID, bool OBF16>
__global__ __launch_bounds__(256, 2) void gemm4p(
    const u16* __restrict__ A, const u16* __restrict__ BT,
    const float* __restrict__ bias, const float* __restrict__ resid,
    void* __restrict__ Cv, int M, int N, int K) {
  __shared__ u16 As[2][2][4096];
  __shared__ u16 Bs[2][2][4096];
  const int tid = threadIdx.x;
  const int lane = tid & 63, wave = tid >> 6;
  const int wm = wave >> 1, wn = wave & 1;
  const int m0 = blockIdx.x * 128, n0 = blockIdx.y * 128;
  const int NT = K >> 6;
  const int sr = tid >> 2;
  const int ssc = (((tid & 3) ^ ((tid >> 3) & 3)) * 8);  // pre-swizzled chunk
  const u16* Abase = A + (size_t)(m0 + sr) * K + ssc;
  const u16* Bbase = BT + (size_t)(n0 + sr) * K + ssc;
  const int rg = (((lane >> 4) ^ ((lane >> 1) & 3)) * 8);

  f32x4 acc[4][4] = {};
  short8v aP0, aP1, aN0, aN1;
  short8v bP0, bP1, bP2, bP3, bN0, bN1, bN2, bN3;

  STAGE_A4(0, 0, 0); STAGE_B4(0, 0, 0);
  STAGE_A4(0, 1, 0); STAGE_B4(0, 1, 0);
  STAGE_A4(1, 0, 1); STAGE_B4(1, 0, 1);
  asm volatile("s_waitcnt vmcnt(8)" ::: "memory");
  BARRIER;
  MEMFENCE;
  aP0 = LDA4_(0, 0, 0); aP1 = LDA4_(0, 0, 1);
  bP0 = LDB4_(0, 0, 0); bP1 = LDB4_(0, 0, 1);
  bP2 = LDB4_(0, 0, 2); bP3 = LDB4_(0, 0, 3);

  int kt = 0;
  for (; kt < NT - 2; ++kt) {
    TILE4P(kt & 1, kt, true, true, "vmcnt(6)", "vmcnt(6)", true, "lgkmcnt(6)");
  }
  TILE4P(kt & 1, kt, true, false, "vmcnt(6)", "vmcnt(4)", true, "lgkmcnt(6)");
  ++kt;
  TILE4P(kt & 1, kt, false, false, "vmcnt(0)", "vmcnt(0)", false, "lgkmcnt(0)");

  #pragma unroll
  for (int f = 0; f < 4; ++f) {
    #pragma unroll
    for (int n = 0; n < 4; ++n) {
      const int col = n0 + wn * 64 + n * 16 + (lane & 15);
      #pragma unroll
      for (int r = 0; r < 4; ++r) {
        const int row = m0 + wm * 64 + f * 16 + (lane >> 4) * 4 + r;
        float v = acc[f][n][r];
        if (BIAS) v += bias[col];
        if (RELU) v = fmaxf(v, 0.f);
        if (RESID) v += resid[(size_t)row * N + col];
        if (OBF16)
          ((u16*)Cv)[(size_t)row * N + col] = f2bf(v);
        else
          ((float*)Cv)[(size_t)row * N + col] = v;
      }
    }
  }
}

// ---------------------------------------------------------------------------
// Fallback fp32 GEMM for LM head (A bf16, B fp32 [K][N], +bias)
// ---------------------------------------------------------------------------
__global__ __launch_bounds__(256) void gemm_fb(
    const u16* __restrict__ A, const float* __restrict__ B,
    const float* __restrict__ bias, float* __restrict__ C, int M, int N, int K) {
  __shared__ alignas(16) float Asm[16][68];
  __shared__ alignas(16) float Bsm[16][68];
  const int tid = threadIdx.x;
  const int tx = tid & 15, ty = tid >> 4;
  const int m0 = blockIdx.y * 64, n0 = blockIdx.x * 64;
  const int ar = tid >> 2, ac = (tid & 3) * 4;
  const int br = tid >> 4, bc = (tid & 15) * 4;
  float acc[4][4] = {};
  for (int k0 = 0; k0 < K; k0 += 16) {
    ushort4 au = *(const ushort4*)(A + (size_t)(m0 + ar) * K + k0 + ac);
    float4 bv = *(const float4*)(B + (size_t)(k0 + br) * N + n0 + bc);
    Asm[ac + 0][ar] = bf2f_lo(au.x);
    Asm[ac + 1][ar] = bf2f_lo(au.y);
    Asm[ac + 2][ar] = bf2f_lo(au.z);
    Asm[ac + 3][ar] = bf2f_lo(au.w);
    *(float4*)&Bsm[br][bc] = bv;
    __syncthreads();
    #pragma unroll
    for (int kk = 0; kk < 16; ++kk) {
      float4 a = *(const float4*)&Asm[kk][ty * 4];
      float4 b = *(const float4*)&Bsm[kk][tx * 4];
      acc[0][0] += a.x * b.x; acc[0][1] += a.x * b.y; acc[0][2] += a.x * b.z; acc[0][3] += a.x * b.w;
      acc[1][0] += a.y * b.x; acc[1][1] += a.y * b.y; acc[1][2] += a.y * b.z; acc[1][3] += a.y * b.w;
      acc[2][0] += a.z * b.x; acc[2][1] += a.z * b.y; acc[2][2] += a.z * b.z; acc[2][3] += a.z * b.w;
      acc[3][0] += a.w * b.x; acc[3][1] += a.w * b.y; acc[3][2] += a.w * b.z; acc[3][3] += a.w * b.w;
    }
    __syncthreads();
  }
  #pragma unroll
  for (int i = 0; i < 4; ++i) {
    const int m = m0 + ty * 4 + i;
    #pragma unroll
    for (int j = 0; j < 4; ++j) {
      const int n = n0 + tx * 4 + j;
      C[(size_t)m * N + n] = acc[i][j] + bias[n];
    }
  }
}

// ---------------------------------------------------------------------------
// MFMA flash attention — 8 waves, 128 q-rows/block, KB=64.
// qkv rows of 3072: [0..1023]=Q, [1024..2047]=K, [2048..3071]=V.
// vt: [h*64+e][b*S+s] bf16 (stride MM), from transpose_v.
// ---------------------------------------------------------------------------
__global__ __launch_bounds__(512) void attn_mfma(
    const u16* __restrict__ qkv, const u16* __restrict__ vt,
    u16* __restrict__ o) {
  __shared__ alignas(16) u16 Ksh[64 * 64];
  __shared__ alignas(16) u16 Vsh[64 * 64];
  __shared__ unsigned Plds[8][16 * 41];
  __shared__ float bcast[8][16];
  const int tid = threadIdx.x;
  const int lane = tid & 63, wave = tid >> 6;
  const int g = lane >> 4, qi = lane & 15;
  const int qt = (SS / 128 - 1) - blockIdx.x;   // heaviest first
  const int h = blockIdx.y, b = blockIdx.z;
  const int q0w = qt * 128 + wave * 16;
  const int ktmax = 2 * qt + 1;

  short8v qf0, qf1;
  {
    const u16* qp = qkv + ((size_t)b * SS + q0w + qi) * 3072 + h * DHH + g * 8;
    qf0 = *(const short8v*)qp;
    qf1 = *(const short8v*)(qp + 32);
  }

  f32x4 oacc[4] = {};
  float mrow = -1e30f, lrow = 0.f;

  for (int kt = 0; kt <= ktmax; ++kt) {
    __syncthreads();
    {
      const int row = tid >> 3, ch = tid & 7;
      const int sch = ch ^ (row & 7);
      __builtin_amdgcn_global_load_lds(
          (const guint*)(qkv + ((size_t)b * SS + kt * 64 + row) * 3072 + 1024 + h * DHH + sch * 8),
          (luint*)(Ksh + tid * 8), 16, 0, 0);
      __builtin_amdgcn_global_load_lds(
          (const guint*)(vt + ((size_t)(h * DHH + row)) * MM + b * SS + kt * 64 + sch * 8),
          (luint*)(Vsh + tid * 8), 16, 0, 0);
    }
    __syncthreads();

    const bool active = (kt * 64 <= q0w + 15);
    if (active) {
      f32x4 st[4] = {};
      #pragma unroll
      for (int t = 0; t < 4; ++t) {
        const int row = t * 16 + qi;
        const int swz = (row & 7) << 4;
        short8v kf0 = *(const short8v*)(Ksh + row * 64 + (((g * 16) ^ swz) >> 1));
        short8v kf1 = *(const short8v*)(Ksh + row * 64 + (((64 + g * 16) ^ swz) >> 1));
        st[t] = __builtin_amdgcn_mfma_f32_16x16x32_bf16(kf0, qf0, st[t], 0, 0, 0);
        st[t] = __builtin_amdgcn_mfma_f32_16x16x32_bf16(kf1, qf1, st[t], 0, 0, 0);
      }

      const int diag = q0w + qi - kt * 64;
      if (diag < 63) {
        #pragma unroll
        for (int t = 0; t < 4; ++t)
          #pragma unroll
          for (int r = 0; r < 4; ++r)
            if (t * 16 + 4 * g + r > diag) st[t][r] = -1e30f;
      }

      float mt = st[0][0];
      #pragma unroll
      for (int t = 0; t < 4; ++t)
        #pragma unroll
        for (int r = 0; r < 4; ++r) mt = fmaxf(mt, st[t][r]);
      mt = fmaxf(mt, __shfl_xor(mt, 16));
      mt = fmaxf(mt, __shfl_xor(mt, 32));
      const float mnew = fmaxf(mrow, mt * 0.125f);
      const float corr = __expf(mrow - mnew);
      float pl = 0.f;
      #pragma unroll
      for (int t = 0; t < 4; ++t) {
        #pragma unroll
        for (int r2 = 0; r2 < 2; ++r2) {
          float plo = __expf(fmaf(st[t][2 * r2], 0.125f, -mnew));
          float phi = __expf(fmaf(st[t][2 * r2 + 1], 0.125f, -mnew));
          pl += plo + phi;
          Plds[wave][qi * 41 + 8 * t + 2 * g + r2] =
              (unsigned)f2bf(plo) | ((unsigned)f2bf(phi) << 16);
        }
      }
      pl += __shfl_xor(pl, 16);
      pl += __shfl_xor(pl, 32);
      lrow = lrow * corr + pl;
      mrow = mnew;

      if (g == 0) bcast[wave][qi] = corr;
      float c0 = bcast[wave][g * 4 + 0];
      float c1 = bcast[wave][g * 4 + 1];
      float c2 = bcast[wave][g * 4 + 2];
      float c3 = bcast[wave][g * 4 + 3];
      #pragma unroll
      for (int dvt = 0; dvt < 4; ++dvt) {
        oacc[dvt][0] *= c0; oacc[dvt][1] *= c1;
        oacc[dvt][2] *= c2; oacc[dvt][3] *= c3;
      }

      union U8 { unsigned u[4]; short8v s8; };
      U8 pa0, pa1;
      #pragma unroll
      for (int c = 0; c < 4; ++c) {
        pa0.u[c] = Plds[wave][qi * 41 + g * 4 + c];
        pa1.u[c] = Plds[wave][qi * 41 + 16 + g * 4 + c];
      }
      #pragma unroll
      for (int dvt = 0; dvt < 4; ++dvt) {
        const int row = dvt * 16 + qi;
        const int swz = (row & 7) << 4;
        short8v v0 = *(const short8v*)(Vsh + row * 64 + (((g * 16) ^ swz) >> 1));
        short8v v1 = *(const short8v*)(Vsh + row * 64 + (((64 + g * 16) ^ swz) >> 1));
        oacc[dvt] = __builtin_amdgcn_mfma_f32_16x16x32_bf16(pa0.s8, v0, oacc[dvt], 0, 0, 0);
        oacc[dvt] = __builtin_amdgcn_mfma_f32_16x16x32_bf16(pa1.s8, v1, oacc[dvt], 0, 0, 0);
      }
    }
  }

  if (g == 0) bcast[wave][qi] = 1.f / lrow;
  float i0 = bcast[wave][g * 4 + 0];
  float i1 = bcast[wave][g * 4 + 1];
  float i2 = bcast[wave][g * 4 + 2];
  float i3 = bcast[wave][g * 4 + 3];
  #pragma unroll
  for (int dvt = 0; dvt < 4; ++dvt) {
    const int col = h * DHH + dvt * 16 + qi;
    o[((size_t)b * SS + q0w + g * 4 + 0) * DD + col] = f2bf(oacc[dvt][0] * i0);
    o[((size_t)b * SS + q0w + g * 4 + 1) * DD + col] = f2bf(oacc[dvt][1] * i1);
    o[((size_t)b * SS + q0w + g * 4 + 2) * DD + col] = f2bf(oacc[dvt][2] * i2);
    o[((size_t)b * SS + q0w + g * 4 + 3) * DD + col] = f2bf(oacc[dvt][3] * i3);
  }
}

// ---------------------------------------------------------------------------
extern "C" void kernel_launch(void* const* d_in, const int* in_sizes, int n_in,
                              void* d_out, int out_size, void* d_ws, size_t ws_size,
                              hipStream_t stream) {
  const int* idx = (const int*)d_in[0];
  const float* tok_emb = (const float*)d_in[1];
  const float* pos_emb = (const float*)d_in[2];
  const float* ln1_s = (const float*)d_in[3];
  const float* ln1_b = (const float*)d_in[4];
  const float* wq = (const float*)d_in[5];
  const float* wk = (const float*)d_in[6];
  const float* wv = (const float*)d_in[7];
  const float* wproj = (const float*)d_in[8];
  const float* ln2_s = (const float*)d_in[9];
  const float* ln2_b = (const float*)d_in[10];
  const float* w1 = (const float*)d_in[11];
  const float* b1 = (const float*)d_in[12];
  const float* w2 = (const float*)d_in[13];
  const float* b2 = (const float*)d_in[14];
  const float* lnf_s = (const float*)d_in[15];
  const float* lnf_b = (const float*)d_in[16];
  const float* lm_w = (const float*)d_in[17];
  const float* lm_b = (const float*)d_in[18];

  const size_t MD = (size_t)MM * DD;

  // d_out scratch (all dead before the LM GEMM writes d_out)
  u16* sc0 = (u16*)d_out;
  u16* BTqkv = sc0;                                  // LL x [3072][1024]
  u16* BTp = BTqkv + (size_t)LL * 3072 * DD;
  u16* BTw1 = BTp + (size_t)LL * DD * DD;
  u16* BTw2 = BTw1 + (size_t)LL * DD * 4 * DD;
  u16* qkvb = BTw2 + (size_t)LL * DD * 4 * DD;       // [M][3072]
  u16* vtb = qkvb + (size_t)MM * 3072;               // [1024][4096]
  u16* ob = vtb + MD;
  u16* tmp = ob + MD;                                // [M][4096]

  // d_ws: x fp32 (16MB) + h bf16 (8MB) + BT(lm_w) bf16 (65.5MB) if room
  float* x = (float*)d_ws;
  u16* h = (u16*)((char*)d_ws + MD * 4);
  u16* BTlm = (u16*)((char*)d_ws + MD * 4 + MD * 2);
  const bool big_ws = ws_size >= (MD * 4 + MD * 2 + (size_t)VV * DD * 2);

  const dim3 blk(256);

  convT_kernel<true><<<dim3(DD / 32, DD / 64, LL), blk, 0, stream>>>(
      wq, BTqkv, DD, DD, (size_t)3072 * DD);
  convT_kernel<true><<<dim3(DD / 32, DD / 64, LL), blk, 0, stream>>>(
      wk, BTqkv + (size_t)DD * DD, DD, DD, (size_t)3072 * DD);
  convT_kernel<true><<<dim3(DD / 32, DD / 64, LL), blk, 0, stream>>>(
      wv, BTqkv + (size_t)2 * DD * DD, DD, DD, (size_t)3072 * DD);
  convT_kernel<false><<<dim3(DD / 32, DD / 64, LL), blk, 0, stream>>>(
      wproj, BTp, DD, DD, (size_t)DD * DD);
  convT_kernel<false><<<dim3(4 * DD / 32, DD / 64, LL), blk, 0, stream>>>(
      w1, BTw1, DD, 4 * DD, (size_t)DD * 4 * DD);
  convT_kernel<false><<<dim3(DD / 32, 4 * DD / 64, LL), blk, 0, stream>>>(
      w2, BTw2, 4 * DD, DD, (size_t)4 * DD * DD);
  if (big_ws)
    convT_kernel<false><<<dim3(VV / 32, DD / 64, 1), blk, 0, stream>>>(
        lm_w, BTlm, DD, VV, (size_t)VV * DD);

  embed_kernel<<<(MM * DD / 4 + 255) / 256, blk, 0, stream>>>(idx, tok_emb, pos_emb, x);

  for (int l = 0; l < LL; ++l) {
    ln_bf16_kernel<<<MM, blk, 0, stream>>>(x, ln1_s + l * DD, ln1_b + l * DD, h);
    // Fused Q+K+V (gemm8 256^2): C = h @ [Wq|Wk|Wv], N=3072
    gemm8<false, false, false, true, false><<<dim3((MM / 256) * (3072 / 256)), dim3(512), 0, stream>>>(
        h, BTqkv + (size_t)l * 3072 * DD, nullptr, nullptr, qkvb, MM, 3072, DD);
    transpose_v<<<dim3(MM / 32, DD / 32), blk, 0, stream>>>(qkvb, vtb);
    attn_mfma<<<dim3(SS / 128, HH, BB), dim3(512), 0, stream>>>(qkvb, vtb, ob);
    // Projection + residual (gemm4p 128^2)
    gemm4p<false, false, true, false><<<dim3(MM / 128, DD / 128), blk, 0, stream>>>(
        ob, BTp + (size_t)l * DD * DD, nullptr, x, x, MM, DD, DD);
    ln_bf16_kernel<<<MM, blk, 0, stream>>>(x, ln2_s + l * DD, ln2_b + l * DD, h);
    // MLP1 (gemm8 256^2)
    gemm8<true, true, false, true, false><<<dim3((MM / 256) * (4 * DD / 256)), dim3(512), 0, stream>>>(
        h, BTw1 + (size_t)l * DD * 4 * DD, b1 + (size_t)l * 4 * DD, nullptr, tmp,
        MM, 4 * DD, DD);
    // MLP2 + residual (gemm4p 128^2)
    gemm4p<true, false, true, false><<<dim3(MM / 128, DD / 128), blk, 0, stream>>>(
        tmp, BTw2 + (size_t)l * 4 * DD * DD, b2 + (size_t)l * DD, x, x, MM, DD, 4 * DD);
  }

  ln_bf16_kernel<<<MM, blk, 0, stream>>>(x, lnf_s, lnf_b, h);
  if (big_ws) {
    // LM head (gemm8 256^2, LDS-bounce NT epilogue)
    gemm8<true, false, false, false, true><<<dim3((MM / 256) * (VV / 256)), dim3(512), 0, stream>>>(
        h, BTlm, lm_b, nullptr, (float*)d_out, MM, VV, DD);
  } else {
    gemm_fb<<<dim3(VV / 64, MM / 64), blk, 0, stream>>>(
        h, lm_w, lm_b, (float*)d_out, MM, VV, DD);
  }
}